// Round 2
// baseline (8479.549 us; speedup 1.0000x reference)
//
#include <hip/hip_runtime.h>
#include <hip/hip_bf16.h>

typedef __hip_bfloat16 bf16;

#define D_ 256
#define NHEAD_ 8
#define DH_ 32
#define NQ_ 300
#define NLAYERS_ 6
#define DFF_ 1024
#define NCLS_ 80
#define BS_ 16
#define LM_ 8400
#define BN_ (BS_*NQ_)   // 4800

// ---------------- generic tiled GEMM: C = act(A@W + bias) ----------------
// A: (M,K) f32 ; W: (K,N) f32 ; bias: (N) f32 ; C: (M,N) f32 or bf16
template<bool RELU, bool OUTBF16>
__global__ __launch_bounds__(256) void gemm_kernel(
    const float* __restrict__ A, const float* __restrict__ W,
    const float* __restrict__ bias, void* __restrict__ Cv,
    int M, int K, int N)
{
    float* Cf = (float*)Cv; bf16* Ch = (bf16*)Cv;
    __shared__ float As[16][68];
    __shared__ float Bs[16][68];
    int tid = threadIdx.x;
    int m0 = blockIdx.y*64, n0 = blockIdx.x*64;
    int tm = tid>>4, tn = tid&15;
    float acc[4][4] = {};
    int lam = tid>>2;        // A-load row 0..63
    int lak = (tid&3)*4;     // A-load k quad
    int lbk = tid>>4;        // B-load k 0..15
    int lbn = (tid&15)*4;    // B-load n quad
    for(int k0=0;k0<K;k0+=16){
        {
            int m = m0+lam;
            #pragma unroll
            for(int j=0;j<4;j++){
                int k = k0+lak+j;
                float v=0.f;
                if(m<M && k<K) v = A[(size_t)m*K+k];
                As[lak+j][lam]=v;
            }
        }
        {
            int k = k0+lbk;
            #pragma unroll
            for(int j=0;j<4;j++){
                int n = n0+lbn+j;
                float v=0.f;
                if(k<K && n<N) v = W[(size_t)k*N+n];
                Bs[lbk][lbn+j]=v;
            }
        }
        __syncthreads();
        #pragma unroll
        for(int kk=0;kk<16;kk++){
            float a[4], bb[4];
            #pragma unroll
            for(int i=0;i<4;i++) a[i]=As[kk][tm*4+i];
            #pragma unroll
            for(int j=0;j<4;j++) bb[j]=Bs[kk][tn*4+j];
            #pragma unroll
            for(int i=0;i<4;i++)
                #pragma unroll
                for(int j=0;j<4;j++) acc[i][j] += a[i]*bb[j];
        }
        __syncthreads();
    }
    #pragma unroll
    for(int i=0;i<4;i++){
        int m=m0+tm*4+i; if(m>=M) continue;
        #pragma unroll
        for(int j=0;j<4;j++){
            int n=n0+tn*4+j; if(n>=N) continue;
            float v = acc[i][j] + bias[n];
            if(RELU) v = fmaxf(v,0.f);
            if(OUTBF16) Ch[(size_t)m*N+n]=__float2bfloat16(v);
            else Cf[(size_t)m*N+n]=v;
        }
    }
}

// ---------------- small elementwise kernels ----------------
__global__ void copy_kernel(const float* __restrict__ a, float* __restrict__ o, int n){
    int i = blockIdx.x*blockDim.x+threadIdx.x;
    if(i<n) o[i]=a[i];
}
__global__ void sigmoid_init_kernel(const float* __restrict__ a, float* __restrict__ o, int n){
    int i = blockIdx.x*blockDim.x+threadIdx.x;
    if(i<n){ float x=a[i]; o[i]=1.f/(1.f+expf(-x)); }
}
__global__ void add_kernel(const float* __restrict__ a, const float* __restrict__ b, float* __restrict__ c, int n){
    int i = blockIdx.x*blockDim.x+threadIdx.x;
    if(i<n) c[i]=a[i]+b[i];
}
__global__ void bbox_update_kernel(float* __restrict__ refd, const float* __restrict__ delta, int n){
    int i = blockIdx.x*blockDim.x+threadIdx.x;
    if(i>=n) return;
    float x = refd[i];
    x = fminf(fmaxf(x,0.f),1.f);
    float num = fmaxf(x,1e-5f), den = fmaxf(1.f-x,1e-5f);
    float nd = delta[i] + logf(num/den);
    refd[i] = 1.f/(1.f+expf(-nd));
}
__global__ void write_out_kernel(const float* __restrict__ refd, const float* __restrict__ logits, float* __restrict__ out){
    int i = blockIdx.x*blockDim.x+threadIdx.x;
    if(i<BN_*4) out[i]=refd[i];
    else if(i<BN_*4+BN_*NCLS_) out[i]=logits[i-BN_*4];
}

// ---------------- layernorm with residual: cur = LN(cur + t2)*g + b ----------------
__global__ __launch_bounds__(256) void ln_residual_kernel(
    float* __restrict__ cur, const float* __restrict__ t2,
    const float* __restrict__ g, const float* __restrict__ b)
{
    int row = blockIdx.x; int c = threadIdx.x;
    size_t idx = (size_t)row*D_+c;
    float x = cur[idx] + t2[idx];
    float v1 = x, v2 = x*x;
    #pragma unroll
    for(int o=32;o>0;o>>=1){ v1 += __shfl_down(v1,o,64); v2 += __shfl_down(v2,o,64); }
    __shared__ float s1[4], s2[4], st[2];
    int wid=c>>6, lane=c&63;
    if(lane==0){ s1[wid]=v1; s2[wid]=v2; }
    __syncthreads();
    if(c==0){
        float a=0,d=0;
        #pragma unroll
        for(int i=0;i<4;i++){a+=s1[i]; d+=s2[i];}
        st[0]=a/(float)D_; st[1]=d/(float)D_;
    }
    __syncthreads();
    float m=st[0], var=st[1]-m*m;
    float y = (x-m)*rsqrtf(var+1e-5f)*g[c] + b[c];
    cur[idx]=y;
}

// ---------------- MHA scores+softmax: one block per (b,h,qi) ----------------
__global__ __launch_bounds__(512) void mha_scores_kernel(
    const float* __restrict__ Q, const float* __restrict__ Kt, float* __restrict__ attn)
{
    int x = blockIdx.x;              // ((b*8+h)*300+qi)
    int qi = x%NQ_; int bh = x/NQ_; int h = bh%NHEAD_; int b = bh/NHEAD_;
    int tid = threadIdx.x;
    __shared__ float qs[32]; __shared__ float red[512]; __shared__ float st[2];
    if(tid<32) qs[tid]=Q[((size_t)(b*NQ_+qi))*D_ + h*DH_ + tid];
    __syncthreads();
    float d=-1e30f;
    if(tid<NQ_){
        const float* kr = Kt + ((size_t)(b*NQ_+tid))*D_ + h*DH_;
        float s=0.f;
        #pragma unroll
        for(int c2=0;c2<32;c2++) s += qs[c2]*kr[c2];
        d = s*0.17677669529663687f;  // 1/sqrt(32)
    }
    red[tid]=d; __syncthreads();
    for(int s2=256;s2>0;s2>>=1){ if(tid<s2) red[tid]=fmaxf(red[tid],red[tid+s2]); __syncthreads(); }
    if(tid==0) st[0]=red[0];
    __syncthreads();
    float p = (tid<NQ_)? expf(d-st[0]) : 0.f;
    red[tid]=p; __syncthreads();
    for(int s2=256;s2>0;s2>>=1){ if(tid<s2) red[tid]+=red[tid+s2]; __syncthreads(); }
    if(tid==0) st[1]=red[0];
    __syncthreads();
    if(tid<NQ_) attn[(size_t)x*NQ_+tid] = p/st[1];
}

// ---------------- MHA apply: o[b,qi,h*32+c] = sum_k P*V ----------------
__global__ __launch_bounds__(256) void mha_apply_kernel(
    const float* __restrict__ attn, const float* __restrict__ V, float* __restrict__ o)
{
    int row = blockIdx.x;            // b*300+qi
    int b = row/NQ_, qi = row%NQ_;
    int tid = threadIdx.x; int h = tid>>5;
    __shared__ float pw[NHEAD_*NQ_];
    for(int idx=tid; idx<NHEAD_*NQ_; idx+=256){
        int hh=idx/NQ_, k=idx%NQ_;
        pw[idx]=attn[((size_t)((b*NHEAD_+hh)*NQ_)+qi)*NQ_+k];
    }
    __syncthreads();
    float acc=0.f;
    const float* Vb = V + (size_t)b*NQ_*D_;
    for(int k=0;k<NQ_;k++) acc += pw[h*NQ_+k]*Vb[(size_t)k*D_+tid];
    o[(size_t)row*D_+tid]=acc;
}

// ---------------- deformable attn: per-(row,head) softmax of attw ----------------
__global__ void attw_softmax_kernel(float* __restrict__ aw){
    int t = blockIdx.x*blockDim.x+threadIdx.x;
    if(t>=BN_*NHEAD_) return;
    int row=t/NHEAD_, h=t%NHEAD_;
    float* p = aw + (size_t)row*96 + h*12;
    float m=-1e30f;
    #pragma unroll
    for(int i=0;i<12;i++) m=fmaxf(m,p[i]);
    float e[12]; float s=0.f;
    #pragma unroll
    for(int i=0;i<12;i++){ e[i]=expf(p[i]-m); s+=e[i]; }
    float inv=1.f/s;
    #pragma unroll
    for(int i=0;i<12;i++) p[i]=e[i]*inv;
}

// ---------------- deformable sampling ----------------
__global__ __launch_bounds__(256) void deform_sample_kernel(
    const float* __restrict__ refd, const float* __restrict__ offs,
    const float* __restrict__ attw, const bf16* __restrict__ value,
    float* __restrict__ outacc)
{
    int row = blockIdx.x; int b = row/NQ_;
    int tid = threadIdx.x; int h = tid>>5, c = tid&31;
    __shared__ float so[192], sa[96], sr[4];
    if(tid<192) so[tid]=offs[(size_t)row*192+tid];
    if(tid<96)  sa[tid]=attw[(size_t)row*96+tid];
    if(tid<4)   sr[tid]=refd[(size_t)row*4+tid];
    __syncthreads();
    float cx=sr[0], cy=sr[1], rw=sr[2], rh=sr[3];
    const int HS[3]={80,40,20}, WS[3]={80,40,20}, ST[3]={0,6400,8000};
    float acc=0.f;
    const bf16* vb = value + (size_t)b*LM_*D_ + h*DH_ + c;
    for(int lv=0;lv<3;lv++){
        int Hl=HS[lv], Wl=WS[lv], st=ST[lv];
        #pragma unroll
        for(int pt=0;pt<4;pt++){
            int oi = ((h*3+lv)*4+pt)*2;
            float ox=so[oi], oy=so[oi+1];
            float wa=sa[h*12+lv*4+pt];
            float lx = cx + ox*0.25f*rw*0.5f;
            float ly = cy + oy*0.25f*rh*0.5f;
            float x = lx*(float)Wl - 0.5f, y = ly*(float)Hl - 0.5f;
            float x0f=floorf(x), y0f=floorf(y);
            float wx=x-x0f, wy=y-y0f;
            int x0=(int)x0f, y0=(int)y0f;
            #pragma unroll
            for(int dy=0;dy<2;dy++){
                #pragma unroll
                for(int dx=0;dx<2;dx++){
                    int xi=x0+dx, yi=y0+dy;
                    if(xi>=0 && xi<Wl && yi>=0 && yi<Hl){
                        float w = (dx? wx : 1.f-wx)*(dy? wy : 1.f-wy);
                        int lin = yi*Wl+xi;
                        acc += __bfloat162float(vb[(size_t)(st+lin)*D_]) * (w*wa);
                    }
                }
            }
        }
    }
    outacc[(size_t)row*D_+tid]=acc;
}

// ---------------- host side ----------------
static void gemm_f32(const float*A, const float*W, const float*b, float*C,
                     int M,int K,int N, hipStream_t s, bool relu){
    dim3 g((N+63)/64,(M+63)/64);
    if(relu) gemm_kernel<true,false><<<g,256,0,s>>>(A,W,b,C,M,K,N);
    else     gemm_kernel<false,false><<<g,256,0,s>>>(A,W,b,C,M,K,N);
}

extern "C" void kernel_launch(void* const* d_in, const int* in_sizes, int n_in,
                              void* d_out, int out_size, void* d_ws, size_t ws_size,
                              hipStream_t stream) {
    // inputs in setup_inputs() dict order (all float32 per reference)
    const float* tgt   = (const float*)d_in[0];
    const float* rpu   = (const float*)d_in[1];
    const float* mem   = (const float*)d_in[2];
    const float* sa_wq = (const float*)d_in[3];
    const float* sa_wk = (const float*)d_in[4];
    const float* sa_wv = (const float*)d_in[5];
    const float* sa_wo = (const float*)d_in[6];
    const float* val_w = (const float*)d_in[7];
    const float* out_w = (const float*)d_in[8];
    const float* bb_w1 = (const float*)d_in[9];
    const float* bb_w2 = (const float*)d_in[10];
    const float* sa_bq = (const float*)d_in[11];
    const float* sa_bk = (const float*)d_in[12];
    const float* sa_bv = (const float*)d_in[13];
    const float* sa_bo = (const float*)d_in[14];
    const float* ln1_b = (const float*)d_in[15];
    const float* ln2_b = (const float*)d_in[16];
    const float* ln3_b = (const float*)d_in[17];
    const float* val_b = (const float*)d_in[18];
    const float* out_b = (const float*)d_in[19];
    const float* ffn_b2= (const float*)d_in[20];
    const float* bb_b1 = (const float*)d_in[21];
    const float* bb_b2 = (const float*)d_in[22];
    const float* ln1_g = (const float*)d_in[23];
    const float* ln2_g = (const float*)d_in[24];
    const float* ln3_g = (const float*)d_in[25];
    const float* off_w = (const float*)d_in[26];
    const float* off_b = (const float*)d_in[27];
    const float* attw_w= (const float*)d_in[28];
    const float* attw_b= (const float*)d_in[29];
    const float* ffn_w1= (const float*)d_in[30];
    const float* ffn_b1= (const float*)d_in[31];
    const float* ffn_w2= (const float*)d_in[32];
    const float* bb_w3 = (const float*)d_in[33];
    const float* bb_b3 = (const float*)d_in[34];
    const float* sc_w  = (const float*)d_in[35];
    const float* sc_b  = (const float*)d_in[36];
    const float* qp_w1 = (const float*)d_in[37];
    const float* qp_b1 = (const float*)d_in[38];
    const float* qp_w2 = (const float*)d_in[39];
    const float* qp_b2 = (const float*)d_in[40];

    const size_t BND = (size_t)BN_*D_;
    float* ws = (float*)d_ws;
    float* cur    = ws;
    float* pos    = cur + BND;
    float* qbuf   = pos + BND;
    float* t2     = qbuf+ BND;
    float* tmp    = t2  + BND;
    float* Qh     = tmp + BND;
    float* Kh     = Qh  + BND;
    float* Vh     = Kh  + BND;
    float* offsb  = Vh  + BND;
    float* attwb  = offsb+ (size_t)BN_*192;
    float* refd   = attwb+ (size_t)BN_*96;
    float* delta  = refd + (size_t)BN_*4;
    float* logitsb= delta+ (size_t)BN_*4;
    float* U      = logitsb + (size_t)BN_*NCLS_;  // union region, 17.2M floats
    // phase-disjoint aliases in U:
    float* hid512 = U;            // BN*512 floats  (query-pos MLP hidden)
    float* attn   = U;            // 11.52M floats  (MHA probs)
    bf16*  value  = (bf16*)U;     // 34.4M bf16     (deform value projection)
    float* ffnh   = U;            // BN*1024 floats (FFN hidden)
    float* bb1    = Qh;           // bbox-head hiddens alias Q/K (dead by then)
    float* bb2    = Kh;

    const int nBN_D = (int)BND;
    copy_kernel<<<(nBN_D+255)/256,256,0,stream>>>(tgt, cur, nBN_D);
    sigmoid_init_kernel<<<(BN_*4+255)/256,256,0,stream>>>(rpu, refd, BN_*4);

    for(int i=0;i<NLAYERS_;i++){
        // pos = MLP2(refd)
        gemm_f32(refd, qp_w1, qp_b1, hid512, BN_, 4, 512, stream, true);
        gemm_f32(hid512, qp_w2, qp_b2, pos, BN_, 512, D_, stream, false);
        // q = cur + pos
        add_kernel<<<(nBN_D+255)/256,256,0,stream>>>(cur, pos, qbuf, nBN_D);
        // MHA
        gemm_f32(qbuf, sa_wq + (size_t)i*D_*D_, sa_bq + (size_t)i*D_, Qh, BN_, D_, D_, stream, false);
        gemm_f32(qbuf, sa_wk + (size_t)i*D_*D_, sa_bk + (size_t)i*D_, Kh, BN_, D_, D_, stream, false);
        gemm_f32(cur,  sa_wv + (size_t)i*D_*D_, sa_bv + (size_t)i*D_, Vh, BN_, D_, D_, stream, false);
        mha_scores_kernel<<<BS_*NHEAD_*NQ_,512,0,stream>>>(Qh, Kh, attn);
        mha_apply_kernel<<<BN_,256,0,stream>>>(attn, Vh, tmp);
        gemm_f32(tmp, sa_wo + (size_t)i*D_*D_, sa_bo + (size_t)i*D_, t2, BN_, D_, D_, stream, false);
        ln_residual_kernel<<<BN_,256,0,stream>>>(cur, t2, ln1_g + (size_t)i*D_, ln1_b + (size_t)i*D_);
        // deformable attention
        add_kernel<<<(nBN_D+255)/256,256,0,stream>>>(cur, pos, qbuf, nBN_D);
        {
            dim3 g((D_+63)/64,(BS_*LM_+63)/64);
            gemm_kernel<false,true><<<g,256,0,stream>>>(mem, val_w + (size_t)i*D_*D_, val_b + (size_t)i*D_, value, BS_*LM_, D_, D_);
        }
        gemm_f32(qbuf, off_w + (size_t)i*D_*192, off_b + (size_t)i*192, offsb, BN_, D_, 192, stream, false);
        gemm_f32(qbuf, attw_w + (size_t)i*D_*96, attw_b + (size_t)i*96, attwb, BN_, D_, 96, stream, false);
        attw_softmax_kernel<<<(BN_*NHEAD_+255)/256,256,0,stream>>>(attwb);
        deform_sample_kernel<<<BN_,256,0,stream>>>(refd, offsb, attwb, value, tmp);
        gemm_f32(tmp, out_w + (size_t)i*D_*D_, out_b + (size_t)i*D_, t2, BN_, D_, D_, stream, false);
        ln_residual_kernel<<<BN_,256,0,stream>>>(cur, t2, ln2_g + (size_t)i*D_, ln2_b + (size_t)i*D_);
        // FFN
        gemm_f32(cur, ffn_w1 + (size_t)i*D_*DFF_, ffn_b1 + (size_t)i*DFF_, ffnh, BN_, D_, DFF_, stream, true);
        gemm_f32(ffnh, ffn_w2 + (size_t)i*DFF_*D_, ffn_b2 + (size_t)i*D_, t2, BN_, DFF_, D_, stream, false);
        ln_residual_kernel<<<BN_,256,0,stream>>>(cur, t2, ln3_g + (size_t)i*D_, ln3_b + (size_t)i*D_);
        // bbox head
        gemm_f32(cur, bb_w1 + (size_t)i*D_*D_, bb_b1 + (size_t)i*D_, bb1, BN_, D_, D_, stream, true);
        gemm_f32(bb1, bb_w2 + (size_t)i*D_*D_, bb_b2 + (size_t)i*D_, bb2, BN_, D_, D_, stream, true);
        gemm_f32(bb2, bb_w3 + (size_t)i*D_*4, bb_b3 + (size_t)i*4, delta, BN_, D_, 4, stream, false);
        bbox_update_kernel<<<(BN_*4+255)/256,256,0,stream>>>(refd, delta, BN_*4);
    }
    // final logits from layer NLAYERS-1 params
    gemm_f32(cur, sc_w + (size_t)(NLAYERS_-1)*D_*NCLS_, sc_b + (size_t)(NLAYERS_-1)*NCLS_, logitsb, BN_, D_, NCLS_, stream, false);
    int tot = BN_*4 + BN_*NCLS_;
    write_out_kernel<<<(tot+255)/256,256,0,stream>>>(refd, logitsb, (float*)d_out);
}

// Round 3
// 5444.447 us; speedup vs baseline: 1.5575x; 1.5575x over previous
//
#include <hip/hip_runtime.h>
#include <hip/hip_bf16.h>

typedef __hip_bfloat16 bf16;
typedef short short8 __attribute__((ext_vector_type(8)));
typedef short short4v __attribute__((ext_vector_type(4)));
typedef float float4v __attribute__((ext_vector_type(4)));

#define D_ 256
#define NHEAD_ 8
#define DH_ 32
#define NQ_ 300
#define NLAYERS_ 6
#define DFF_ 1024
#define NCLS_ 80
#define BS_ 16
#define LM_ 8400
#define BN_ (BS_*NQ_)   // 4800

static __device__ __forceinline__ short f2bf(float x){
    union{float f; unsigned u;} v; v.f = x;
    unsigned r = v.u + 0x7FFF + ((v.u>>16)&1);
    return (short)(r>>16);
}

// ================= MFMA bf16 GEMM: C = act(A@W + bias) =================
// A: (M,K) f32 ; WT: (N,K) bf16 (pre-transposed) ; bias: (N) f32
// C: (M,N) f32 or bf16.  K must be a multiple of 32.
#define LSTR 40   // LDS row stride in bf16 elems (80 B)

template<bool RELU, bool OUTBF16>
__global__ __launch_bounds__(256) void mfma_gemm_kernel(
    const float* __restrict__ A, const short* __restrict__ WT,
    const float* __restrict__ bias, void* __restrict__ Cv,
    int M, int K, int N)
{
    __shared__ short As[128*LSTR];
    __shared__ short Bs[128*LSTR];
    int tid = threadIdx.x;
    int lane = tid&63, wave = tid>>6;
    int m0 = blockIdx.y*128, n0 = blockIdx.x*128;
    int wm = (wave>>1)*64, wn = (wave&1)*64;
    int lr = lane&15, lq = lane>>4;
    float4v acc[4][4];
    #pragma unroll
    for(int i=0;i<4;i++)
        #pragma unroll
        for(int j=0;j<4;j++){ acc[i][j].x=0.f; acc[i][j].y=0.f; acc[i][j].z=0.f; acc[i][j].w=0.f; }

    for(int k0=0;k0<K;k0+=32){
        // ---- stage A tile: 128x32, f32 -> bf16 ----
        #pragma unroll
        for(int it=0; it<4; ++it){
            int idx = (it*256+tid)*4;
            int r = idx>>5, kk = idx&31;
            int gm = m0+r;
            float4v v; v.x=0.f;v.y=0.f;v.z=0.f;v.w=0.f;
            if(gm<M) v = *(const float4v*)(A + (size_t)gm*K + (k0+kk));
            short4v h; h.x=f2bf(v.x); h.y=f2bf(v.y); h.z=f2bf(v.z); h.w=f2bf(v.w);
            *(short4v*)(&As[r*LSTR+kk]) = h;
        }
        // ---- stage B tile: 128(n) x 32(k) bf16 from WT ----
        #pragma unroll
        for(int it=0; it<2; ++it){
            int idx = (it*256+tid)*8;
            int r = idx>>5, kk = idx&31;
            int gn = n0+r;
            short8 v = {};
            if(gn<N) v = *(const short8*)(WT + (size_t)gn*K + (k0+kk));
            *(short8*)(&Bs[r*LSTR+kk]) = v;
        }
        __syncthreads();
        short8 af[4], bfr[4];
        #pragma unroll
        for(int mi=0;mi<4;mi++) af[mi]  = *(const short8*)(&As[(wm+mi*16+lr)*LSTR + lq*8]);
        #pragma unroll
        for(int ni=0;ni<4;ni++) bfr[ni] = *(const short8*)(&Bs[(wn+ni*16+lr)*LSTR + lq*8]);
        #pragma unroll
        for(int mi=0;mi<4;mi++)
            #pragma unroll
            for(int ni=0;ni<4;ni++)
                acc[mi][ni] = __builtin_amdgcn_mfma_f32_16x16x32_bf16(af[mi], bfr[ni], acc[mi][ni], 0,0,0);
        __syncthreads();
    }
    float* Cf=(float*)Cv; bf16* Ch=(bf16*)Cv;
    #pragma unroll
    for(int mi=0;mi<4;mi++){
        #pragma unroll
        for(int r=0;r<4;r++){
            int gm = m0+wm+mi*16+lq*4+r;
            if(gm>=M) continue;
            #pragma unroll
            for(int ni=0;ni<4;ni++){
                int gn = n0+wn+ni*16+lr;
                if(gn>=N) continue;
                float v = acc[mi][ni][r] + bias[gn];
                if(RELU) v = fmaxf(v,0.f);
                if(OUTBF16) Ch[(size_t)gm*N+gn]=__float2bfloat16(v);
                else        Cf[(size_t)gm*N+gn]=v;
            }
        }
    }
}

// ============== batched weight transpose f32[K][N] -> bf16[N][K] ==============
struct TDesc { const float* src; size_t dst_off; int K, N, tile_base; };
struct TPack { TDesc d[12]; };

__global__ __launch_bounds__(256) void transpose_pack_kernel(TPack p, short* __restrict__ WT){
    int blk = blockIdx.x;
    int di = 0;
    for(int i=0;i<12;i++){ if(blk >= p.d[i].tile_base) di = i; }
    TDesc d = p.d[di];
    int rel = blk - d.tile_base;
    int ntx = (d.N+31)/32;
    int tn = (rel % ntx)*32, tk = (rel / ntx)*32;
    __shared__ float t[32][33];
    int tx = threadIdx.x&31, ty = threadIdx.x>>5;
    for(int i=0;i<32;i+=8){
        int k = tk+ty+i, n = tn+tx;
        t[ty+i][tx] = (k<d.K && n<d.N)? d.src[(size_t)k*d.N+n] : 0.f;
    }
    __syncthreads();
    short* out = WT + d.dst_off;
    for(int i=0;i<32;i+=8){
        int n = tn+ty+i, k = tk+tx;
        if(n<d.N && k<d.K) out[(size_t)n*d.K+k] = f2bf(t[tx][ty+i]);
    }
}

// ================= SIMT GEMM (kept for tiny K/N) =================
template<bool RELU>
__global__ __launch_bounds__(256) void gemm_kernel(
    const float* __restrict__ A, const float* __restrict__ W,
    const float* __restrict__ bias, float* __restrict__ Cf,
    int M, int K, int N)
{
    __shared__ float As[16][68];
    __shared__ float Bs[16][68];
    int tid = threadIdx.x;
    int m0 = blockIdx.y*64, n0 = blockIdx.x*64;
    int tm = tid>>4, tn = tid&15;
    float acc[4][4] = {};
    int lam = tid>>2;
    int lak = (tid&3)*4;
    int lbk = tid>>4;
    int lbn = (tid&15)*4;
    for(int k0=0;k0<K;k0+=16){
        {
            int m = m0+lam;
            #pragma unroll
            for(int j=0;j<4;j++){
                int k = k0+lak+j;
                float v=0.f;
                if(m<M && k<K) v = A[(size_t)m*K+k];
                As[lak+j][lam]=v;
            }
        }
        {
            int k = k0+lbk;
            #pragma unroll
            for(int j=0;j<4;j++){
                int n = n0+lbn+j;
                float v=0.f;
                if(k<K && n<N) v = W[(size_t)k*N+n];
                Bs[lbk][lbn+j]=v;
            }
        }
        __syncthreads();
        #pragma unroll
        for(int kk=0;kk<16;kk++){
            float a[4], bb[4];
            #pragma unroll
            for(int i=0;i<4;i++) a[i]=As[kk][tm*4+i];
            #pragma unroll
            for(int j=0;j<4;j++) bb[j]=Bs[kk][tn*4+j];
            #pragma unroll
            for(int i=0;i<4;i++)
                #pragma unroll
                for(int j=0;j<4;j++) acc[i][j] += a[i]*bb[j];
        }
        __syncthreads();
    }
    #pragma unroll
    for(int i=0;i<4;i++){
        int m=m0+tm*4+i; if(m>=M) continue;
        #pragma unroll
        for(int j=0;j<4;j++){
            int n=n0+tn*4+j; if(n>=N) continue;
            float v = acc[i][j] + bias[n];
            if(RELU) v = fmaxf(v,0.f);
            Cf[(size_t)m*N+n]=v;
        }
    }
}

// ---------------- small elementwise kernels ----------------
__global__ void copy_kernel(const float* __restrict__ a, float* __restrict__ o, int n){
    int i = blockIdx.x*blockDim.x+threadIdx.x;
    if(i<n) o[i]=a[i];
}
__global__ void sigmoid_init_kernel(const float* __restrict__ a, float* __restrict__ o, int n){
    int i = blockIdx.x*blockDim.x+threadIdx.x;
    if(i<n){ float x=a[i]; o[i]=1.f/(1.f+expf(-x)); }
}
__global__ void add_kernel(const float* __restrict__ a, const float* __restrict__ b, float* __restrict__ c, int n){
    int i = blockIdx.x*blockDim.x+threadIdx.x;
    if(i<n) c[i]=a[i]+b[i];
}
__global__ void bbox_update_kernel(float* __restrict__ refd, const float* __restrict__ delta, int n){
    int i = blockIdx.x*blockDim.x+threadIdx.x;
    if(i>=n) return;
    float x = refd[i];
    x = fminf(fmaxf(x,0.f),1.f);
    float num = fmaxf(x,1e-5f), den = fmaxf(1.f-x,1e-5f);
    float nd = delta[i] + logf(num/den);
    refd[i] = 1.f/(1.f+expf(-nd));
}
__global__ void write_out_kernel(const float* __restrict__ refd, const float* __restrict__ logits, float* __restrict__ out){
    int i = blockIdx.x*blockDim.x+threadIdx.x;
    if(i<BN_*4) out[i]=refd[i];
    else if(i<BN_*4+BN_*NCLS_) out[i]=logits[i-BN_*4];
}

// ---------------- layernorm with residual ----------------
__global__ __launch_bounds__(256) void ln_residual_kernel(
    float* __restrict__ cur, const float* __restrict__ t2,
    const float* __restrict__ g, const float* __restrict__ b)
{
    int row = blockIdx.x; int c = threadIdx.x;
    size_t idx = (size_t)row*D_+c;
    float x = cur[idx] + t2[idx];
    float v1 = x, v2 = x*x;
    #pragma unroll
    for(int o=32;o>0;o>>=1){ v1 += __shfl_down(v1,o,64); v2 += __shfl_down(v2,o,64); }
    __shared__ float s1[4], s2[4], st[2];
    int wid=c>>6, lane=c&63;
    if(lane==0){ s1[wid]=v1; s2[wid]=v2; }
    __syncthreads();
    if(c==0){
        float a=0,d=0;
        #pragma unroll
        for(int i=0;i<4;i++){a+=s1[i]; d+=s2[i];}
        st[0]=a/(float)D_; st[1]=d/(float)D_;
    }
    __syncthreads();
    float m=st[0], var=st[1]-m*m;
    float y = (x-m)*rsqrtf(var+1e-5f)*g[c] + b[c];
    cur[idx]=y;
}

// ---------------- MHA scores+softmax ----------------
__global__ __launch_bounds__(512) void mha_scores_kernel(
    const float* __restrict__ Q, const float* __restrict__ Kt, float* __restrict__ attn)
{
    int x = blockIdx.x;
    int qi = x%NQ_; int bh = x/NQ_; int h = bh%NHEAD_; int b = bh/NHEAD_;
    int tid = threadIdx.x;
    __shared__ float qs[32]; __shared__ float red[512]; __shared__ float st[2];
    if(tid<32) qs[tid]=Q[((size_t)(b*NQ_+qi))*D_ + h*DH_ + tid];
    __syncthreads();
    float d=-1e30f;
    if(tid<NQ_){
        const float* kr = Kt + ((size_t)(b*NQ_+tid))*D_ + h*DH_;
        float s=0.f;
        #pragma unroll
        for(int c2=0;c2<32;c2++) s += qs[c2]*kr[c2];
        d = s*0.17677669529663687f;
    }
    red[tid]=d; __syncthreads();
    for(int s2=256;s2>0;s2>>=1){ if(tid<s2) red[tid]=fmaxf(red[tid],red[tid+s2]); __syncthreads(); }
    if(tid==0) st[0]=red[0];
    __syncthreads();
    float p = (tid<NQ_)? expf(d-st[0]) : 0.f;
    red[tid]=p; __syncthreads();
    for(int s2=256;s2>0;s2>>=1){ if(tid<s2) red[tid]+=red[tid+s2]; __syncthreads(); }
    if(tid==0) st[1]=red[0];
    __syncthreads();
    if(tid<NQ_) attn[(size_t)x*NQ_+tid] = p/st[1];
}

// ---------------- MHA apply ----------------
__global__ __launch_bounds__(256) void mha_apply_kernel(
    const float* __restrict__ attn, const float* __restrict__ V, float* __restrict__ o)
{
    int row = blockIdx.x;
    int b = row/NQ_, qi = row%NQ_;
    int tid = threadIdx.x; int h = tid>>5;
    __shared__ float pw[NHEAD_*NQ_];
    for(int idx=tid; idx<NHEAD_*NQ_; idx+=256){
        int hh=idx/NQ_, k=idx%NQ_;
        pw[idx]=attn[((size_t)((b*NHEAD_+hh)*NQ_)+qi)*NQ_+k];
    }
    __syncthreads();
    float acc=0.f;
    const float* Vb = V + (size_t)b*NQ_*D_;
    for(int k=0;k<NQ_;k++) acc += pw[h*NQ_+k]*Vb[(size_t)k*D_+tid];
    o[(size_t)row*D_+tid]=acc;
}

// ---------------- deform attw softmax ----------------
__global__ void attw_softmax_kernel(float* __restrict__ aw){
    int t = blockIdx.x*blockDim.x+threadIdx.x;
    if(t>=BN_*NHEAD_) return;
    int row=t/NHEAD_, h=t%NHEAD_;
    float* p = aw + (size_t)row*96 + h*12;
    float m=-1e30f;
    #pragma unroll
    for(int i=0;i<12;i++) m=fmaxf(m,p[i]);
    float e[12]; float s=0.f;
    #pragma unroll
    for(int i=0;i<12;i++){ e[i]=expf(p[i]-m); s+=e[i]; }
    float inv=1.f/s;
    #pragma unroll
    for(int i=0;i<12;i++) p[i]=e[i]*inv;
}

// ---------------- deformable sampling ----------------
__global__ __launch_bounds__(256) void deform_sample_kernel(
    const float* __restrict__ refd, const float* __restrict__ offs,
    const float* __restrict__ attw, const bf16* __restrict__ value,
    float* __restrict__ outacc)
{
    int row = blockIdx.x; int b = row/NQ_;
    int tid = threadIdx.x; int h = tid>>5, c = tid&31;
    __shared__ float so[192], sa[96], sr[4];
    if(tid<192) so[tid]=offs[(size_t)row*192+tid];
    if(tid<96)  sa[tid]=attw[(size_t)row*96+tid];
    if(tid<4)   sr[tid]=refd[(size_t)row*4+tid];
    __syncthreads();
    float cx=sr[0], cy=sr[1], rw=sr[2], rh=sr[3];
    const int HS[3]={80,40,20}, WS[3]={80,40,20}, ST[3]={0,6400,8000};
    float acc=0.f;
    const bf16* vb = value + (size_t)b*LM_*D_ + h*DH_ + c;
    for(int lv=0;lv<3;lv++){
        int Hl=HS[lv], Wl=WS[lv], st=ST[lv];
        #pragma unroll
        for(int pt=0;pt<4;pt++){
            int oi = ((h*3+lv)*4+pt)*2;
            float ox=so[oi], oy=so[oi+1];
            float wa=sa[h*12+lv*4+pt];
            float lx = cx + ox*0.25f*rw*0.5f;
            float ly = cy + oy*0.25f*rh*0.5f;
            float x = lx*(float)Wl - 0.5f, y = ly*(float)Hl - 0.5f;
            float x0f=floorf(x), y0f=floorf(y);
            float wx=x-x0f, wy=y-y0f;
            int x0=(int)x0f, y0=(int)y0f;
            #pragma unroll
            for(int dy=0;dy<2;dy++){
                #pragma unroll
                for(int dx=0;dx<2;dx++){
                    int xi=x0+dx, yi=y0+dy;
                    if(xi>=0 && xi<Wl && yi>=0 && yi<Hl){
                        float w = (dx? wx : 1.f-wx)*(dy? wy : 1.f-wy);
                        int lin = yi*Wl+xi;
                        acc += __bfloat162float(vb[(size_t)(st+lin)*D_]) * (w*wa);
                    }
                }
            }
        }
    }
    outacc[(size_t)row*D_+tid]=acc;
}

// ---------------- host helpers ----------------
static void gemm_simt(const float*A, const float*W, const float*b, float*C,
                      int M,int K,int N, hipStream_t s, bool relu){
    dim3 g((N+63)/64,(M+63)/64);
    if(relu) gemm_kernel<true><<<g,256,0,s>>>(A,W,b,C,M,K,N);
    else     gemm_kernel<false><<<g,256,0,s>>>(A,W,b,C,M,K,N);
}
static void mfma_gemm(const float*A, const short*WT, const float*b, void*C,
                      int M,int K,int N, hipStream_t s, bool relu, bool outbf16){
    dim3 g((N+127)/128,(M+127)/128);
    if(outbf16)      mfma_gemm_kernel<false,true ><<<g,256,0,s>>>(A,WT,b,C,M,K,N);
    else if(relu)    mfma_gemm_kernel<true ,false><<<g,256,0,s>>>(A,WT,b,C,M,K,N);
    else             mfma_gemm_kernel<false,false><<<g,256,0,s>>>(A,WT,b,C,M,K,N);
}
static int ntiles(int K,int N){ return ((N+31)/32)*((K+31)/32); }

extern "C" void kernel_launch(void* const* d_in, const int* in_sizes, int n_in,
                              void* d_out, int out_size, void* d_ws, size_t ws_size,
                              hipStream_t stream) {
    const float* tgt   = (const float*)d_in[0];
    const float* rpu   = (const float*)d_in[1];
    const float* mem   = (const float*)d_in[2];
    const float* sa_wq = (const float*)d_in[3];
    const float* sa_wk = (const float*)d_in[4];
    const float* sa_wv = (const float*)d_in[5];
    const float* sa_wo = (const float*)d_in[6];
    const float* val_w = (const float*)d_in[7];
    const float* out_w = (const float*)d_in[8];
    const float* bb_w1 = (const float*)d_in[9];
    const float* bb_w2 = (const float*)d_in[10];
    const float* sa_bq = (const float*)d_in[11];
    const float* sa_bk = (const float*)d_in[12];
    const float* sa_bv = (const float*)d_in[13];
    const float* sa_bo = (const float*)d_in[14];
    const float* ln1_b = (const float*)d_in[15];
    const float* ln2_b = (const float*)d_in[16];
    const float* ln3_b = (const float*)d_in[17];
    const float* val_b = (const float*)d_in[18];
    const float* out_b = (const float*)d_in[19];
    const float* ffn_b2= (const float*)d_in[20];
    const float* bb_b1 = (const float*)d_in[21];
    const float* bb_b2 = (const float*)d_in[22];
    const float* ln1_g = (const float*)d_in[23];
    const float* ln2_g = (const float*)d_in[24];
    const float* ln3_g = (const float*)d_in[25];
    const float* off_w = (const float*)d_in[26];
    const float* off_b = (const float*)d_in[27];
    const float* attw_w= (const float*)d_in[28];
    const float* attw_b= (const float*)d_in[29];
    const float* ffn_w1= (const float*)d_in[30];
    const float* ffn_b1= (const float*)d_in[31];
    const float* ffn_w2= (const float*)d_in[32];
    const float* bb_w3 = (const float*)d_in[33];
    const float* bb_b3 = (const float*)d_in[34];
    const float* sc_w  = (const float*)d_in[35];
    const float* sc_b  = (const float*)d_in[36];
    const float* qp_w1 = (const float*)d_in[37];
    const float* qp_b1 = (const float*)d_in[38];
    const float* qp_w2 = (const float*)d_in[39];
    const float* qp_b2 = (const float*)d_in[40];

    const size_t BND = (size_t)BN_*D_;
    float* ws = (float*)d_ws;
    float* cur    = ws;
    float* pos    = cur + BND;
    float* qbuf   = pos + BND;
    float* t2     = qbuf+ BND;
    float* tmp    = t2  + BND;
    float* Qh     = tmp + BND;
    float* Kh     = Qh  + BND;
    float* Vh     = Kh  + BND;
    float* offsb  = Vh  + BND;
    float* attwb  = offsb+ (size_t)BN_*192;
    float* refd   = attwb+ (size_t)BN_*96;
    float* delta  = refd + (size_t)BN_*4;
    float* logitsb= delta+ (size_t)BN_*4;
    float* U      = logitsb + (size_t)BN_*NCLS_;   // union region: 17.2M floats
    float* hid512 = U;
    float* attn   = U;
    bf16*  value  = (bf16*)U;
    float* ffnh   = U;
    float* bb1    = Qh;
    float* bb2    = Kh;
    // bf16 transposed-weight buffers after U
    short* WT     = (short*)(U + (size_t)17203200);
    // per-layer slots (in shorts):
    const size_t oWQ=0, oWK=65536, oWV=131072, oWO=196608, oVAL=262144, oOUT=327680,
                 oOFF=393216, oATT=442368, oF1=466944, oF2=729088, oB1=991232, oB2=1056768;
    const size_t WT_LAYER_SZ = 1122304;
    short* qp2T = WT + WT_LAYER_SZ;            // 512x256
    short* scT  = qp2T + 131072;               // 80x256

    const int nBN_D = (int)BND;
    copy_kernel<<<(nBN_D+255)/256,256,0,stream>>>(tgt, cur, nBN_D);
    sigmoid_init_kernel<<<(BN_*4+255)/256,256,0,stream>>>(rpu, refd, BN_*4);

    // one-time transposes: qp_w2 (512x256), sc_w[last] (256x80)
    {
        TPack tp; int base=0;
        tp.d[0] = { qp_w2, (size_t)0, 512, 256, base }; base += ntiles(512,256);
        tp.d[1] = { sc_w + (size_t)(NLAYERS_-1)*D_*NCLS_, (size_t)(scT-qp2T), 256, 80, base }; base += ntiles(256,80);
        for(int i=2;i<12;i++) tp.d[i] = { nullptr, 0, 0, 0, 0x7FFFFFFF };
        transpose_pack_kernel<<<base,256,0,stream>>>(tp, qp2T);
    }

    for(int i=0;i<NLAYERS_;i++){
        // transpose this layer's weights into WT
        {
            TPack tp; int base=0;
            const float* srcs[12] = { sa_wq+(size_t)i*D_*D_, sa_wk+(size_t)i*D_*D_, sa_wv+(size_t)i*D_*D_,
                                      sa_wo+(size_t)i*D_*D_, val_w+(size_t)i*D_*D_, out_w+(size_t)i*D_*D_,
                                      off_w+(size_t)i*D_*192, attw_w+(size_t)i*D_*96,
                                      ffn_w1+(size_t)i*D_*DFF_, ffn_w2+(size_t)i*DFF_*D_,
                                      bb_w1+(size_t)i*D_*D_, bb_w2+(size_t)i*D_*D_ };
            const size_t offs[12] = { oWQ,oWK,oWV,oWO,oVAL,oOUT,oOFF,oATT,oF1,oF2,oB1,oB2 };
            const int Ks[12] = { 256,256,256,256,256,256,256,256,256,1024,256,256 };
            const int Ns[12] = { 256,256,256,256,256,256,192,96,1024,256,256,256 };
            for(int j=0;j<12;j++){
                tp.d[j] = { srcs[j], offs[j], Ks[j], Ns[j], base };
                base += ntiles(Ks[j],Ns[j]);
            }
            transpose_pack_kernel<<<base,256,0,stream>>>(tp, WT);
        }
        // pos = MLP2(refd)
        gemm_simt(refd, qp_w1, qp_b1, hid512, BN_, 4, 512, stream, true);
        mfma_gemm(hid512, qp2T, qp_b2, pos, BN_, 512, D_, stream, false, false);
        add_kernel<<<(nBN_D+255)/256,256,0,stream>>>(cur, pos, qbuf, nBN_D);
        // MHA
        mfma_gemm(qbuf, WT+oWQ, sa_bq+(size_t)i*D_, Qh, BN_, D_, D_, stream, false, false);
        mfma_gemm(qbuf, WT+oWK, sa_bk+(size_t)i*D_, Kh, BN_, D_, D_, stream, false, false);
        mfma_gemm(cur,  WT+oWV, sa_bv+(size_t)i*D_, Vh, BN_, D_, D_, stream, false, false);
        mha_scores_kernel<<<BS_*NHEAD_*NQ_,512,0,stream>>>(Qh, Kh, attn);
        mha_apply_kernel<<<BN_,256,0,stream>>>(attn, Vh, tmp);
        mfma_gemm(tmp, WT+oWO, sa_bo+(size_t)i*D_, t2, BN_, D_, D_, stream, false, false);
        ln_residual_kernel<<<BN_,256,0,stream>>>(cur, t2, ln1_g+(size_t)i*D_, ln1_b+(size_t)i*D_);
        // deformable attention
        add_kernel<<<(nBN_D+255)/256,256,0,stream>>>(cur, pos, qbuf, nBN_D);
        mfma_gemm(mem, WT+oVAL, val_b+(size_t)i*D_, value, BS_*LM_, D_, D_, stream, false, true);
        mfma_gemm(qbuf, WT+oOFF, off_b+(size_t)i*192, offsb, BN_, D_, 192, stream, false, false);
        mfma_gemm(qbuf, WT+oATT, attw_b+(size_t)i*96, attwb, BN_, D_, 96, stream, false, false);
        attw_softmax_kernel<<<(BN_*NHEAD_+255)/256,256,0,stream>>>(attwb);
        deform_sample_kernel<<<BN_,256,0,stream>>>(refd, offsb, attwb, value, tmp);
        mfma_gemm(tmp, WT+oOUT, out_b+(size_t)i*D_, t2, BN_, D_, D_, stream, false, false);
        ln_residual_kernel<<<BN_,256,0,stream>>>(cur, t2, ln2_g+(size_t)i*D_, ln2_b+(size_t)i*D_);
        // FFN
        mfma_gemm(cur, WT+oF1, ffn_b1+(size_t)i*DFF_, ffnh, BN_, D_, DFF_, stream, true, false);
        mfma_gemm(ffnh, WT+oF2, ffn_b2+(size_t)i*D_, t2, BN_, DFF_, D_, stream, false, false);
        ln_residual_kernel<<<BN_,256,0,stream>>>(cur, t2, ln3_g+(size_t)i*D_, ln3_b+(size_t)i*D_);
        // bbox head
        mfma_gemm(cur, WT+oB1, bb_b1+(size_t)i*D_, bb1, BN_, D_, D_, stream, true, false);
        mfma_gemm(bb1, WT+oB2, bb_b2+(size_t)i*D_, bb2, BN_, D_, D_, stream, true, false);
        gemm_simt(bb2, bb_w3+(size_t)i*D_*4, bb_b3+(size_t)i*4, delta, BN_, D_, 4, stream, false);
        bbox_update_kernel<<<(BN_*4+255)/256,256,0,stream>>>(refd, delta, BN_*4);
    }
    mfma_gemm(cur, scT, sc_b+(size_t)(NLAYERS_-1)*NCLS_, logitsb, BN_, D_, NCLS_, stream, false, false);
    int tot = BN_*4 + BN_*NCLS_;
    write_out_kernel<<<(tot+255)/256,256,0,stream>>>(refd, logitsb, (float*)d_out);
}

// Round 4
// 4486.241 us; speedup vs baseline: 1.8901x; 1.2136x over previous
//
#include <hip/hip_runtime.h>
#include <hip/hip_bf16.h>

typedef __hip_bfloat16 bf16;
typedef short short8 __attribute__((ext_vector_type(8)));
typedef short short4v __attribute__((ext_vector_type(4)));
typedef float float4v __attribute__((ext_vector_type(4)));

#define D_ 256
#define NHEAD_ 8
#define DH_ 32
#define NQ_ 300
#define NLAYERS_ 6
#define DFF_ 1024
#define NCLS_ 80
#define BS_ 16
#define LM_ 8400
#define BN_ (BS_*NQ_)   // 4800

static __device__ __forceinline__ short f2bf(float x){
    union{float f; unsigned u;} v; v.f = x;
    unsigned r = v.u + 0x7FFF + ((v.u>>16)&1);
    return (short)(r>>16);
}

// ================= MFMA bf16 GEMM: C = act(A@W + bias) =================
#define LSTR 40   // LDS row stride in bf16 elems (80 B)

template<bool RELU, bool OUTBF16>
__global__ __launch_bounds__(256) void mfma_gemm_kernel(
    const float* __restrict__ A, const short* __restrict__ WT,
    const float* __restrict__ bias, void* __restrict__ Cv,
    int M, int K, int N)
{
    __shared__ short As[128*LSTR];
    __shared__ short Bs[128*LSTR];
    int tid = threadIdx.x;
    int lane = tid&63, wave = tid>>6;
    int m0 = blockIdx.y*128, n0 = blockIdx.x*128;
    int wm = (wave>>1)*64, wn = (wave&1)*64;
    int lr = lane&15, lq = lane>>4;
    float4v acc[4][4];
    #pragma unroll
    for(int i=0;i<4;i++)
        #pragma unroll
        for(int j=0;j<4;j++){ acc[i][j].x=0.f; acc[i][j].y=0.f; acc[i][j].z=0.f; acc[i][j].w=0.f; }

    for(int k0=0;k0<K;k0+=32){
        #pragma unroll
        for(int it=0; it<4; ++it){
            int idx = (it*256+tid)*4;
            int r = idx>>5, kk = idx&31;
            int gm = m0+r;
            float4v v; v.x=0.f;v.y=0.f;v.z=0.f;v.w=0.f;
            if(gm<M) v = *(const float4v*)(A + (size_t)gm*K + (k0+kk));
            short4v h; h.x=f2bf(v.x); h.y=f2bf(v.y); h.z=f2bf(v.z); h.w=f2bf(v.w);
            *(short4v*)(&As[r*LSTR+kk]) = h;
        }
        #pragma unroll
        for(int it=0; it<2; ++it){
            int idx = (it*256+tid)*8;
            int r = idx>>5, kk = idx&31;
            int gn = n0+r;
            short8 v = {};
            if(gn<N) v = *(const short8*)(WT + (size_t)gn*K + (k0+kk));
            *(short8*)(&Bs[r*LSTR+kk]) = v;
        }
        __syncthreads();
        short8 af[4], bfr[4];
        #pragma unroll
        for(int mi=0;mi<4;mi++) af[mi]  = *(const short8*)(&As[(wm+mi*16+lr)*LSTR + lq*8]);
        #pragma unroll
        for(int ni=0;ni<4;ni++) bfr[ni] = *(const short8*)(&Bs[(wn+ni*16+lr)*LSTR + lq*8]);
        #pragma unroll
        for(int mi=0;mi<4;mi++)
            #pragma unroll
            for(int ni=0;ni<4;ni++)
                acc[mi][ni] = __builtin_amdgcn_mfma_f32_16x16x32_bf16(af[mi], bfr[ni], acc[mi][ni], 0,0,0);
        __syncthreads();
    }
    float* Cf=(float*)Cv; bf16* Ch=(bf16*)Cv;
    #pragma unroll
    for(int mi=0;mi<4;mi++){
        #pragma unroll
        for(int r=0;r<4;r++){
            int gm = m0+wm+mi*16+lq*4+r;
            if(gm>=M) continue;
            #pragma unroll
            for(int ni=0;ni<4;ni++){
                int gn = n0+wn+ni*16+lr;
                if(gn>=N) continue;
                float v = acc[mi][ni][r] + bias[gn];
                if(RELU) v = fmaxf(v,0.f);
                if(OUTBF16) Ch[(size_t)gm*N+gn]=__float2bfloat16(v);
                else        Cf[(size_t)gm*N+gn]=v;
            }
        }
    }
}

// ================= fused MHA: S=QK^T, softmax, O=PV (per b,h,qtile) =================
#define QT_  64
#define KP_  304    // 19*16 padded keys for scores
#define KPV_ 320    // 10*32 padded keys for PV
#define KSTR 36
#define VSTR 324
#define PSTR 324

__global__ __launch_bounds__(256) void fused_mha_kernel(
    const float* __restrict__ Q, const float* __restrict__ K,
    const float* __restrict__ V, float* __restrict__ O)
{
    int bh = blockIdx.y; int b = bh>>3, h = bh&7;
    int q0 = blockIdx.x*QT_;
    __shared__ short Qs[QT_*KSTR];
    __shared__ short Ks[KP_*KSTR];
    __shared__ short Vts[DH_*VSTR];
    __shared__ short Ps[QT_*PSTR];
    int tid = threadIdx.x;
    // stage Q tile (64x32) f32->bf16
    for(int idx=tid; idx<QT_*DH_; idx+=256){
        int r = idx>>5, c = idx&31;
        int gq = q0+r;
        float v = (gq<NQ_)? Q[((size_t)(b*NQ_+gq))*D_ + h*DH_ + c] : 0.f;
        Qs[r*KSTR+c] = f2bf(v);
    }
    // stage K (304x32)
    for(int idx=tid; idx<KP_*DH_; idx+=256){
        int r = idx>>5, c = idx&31;
        float v = (r<NQ_)? K[((size_t)(b*NQ_+r))*D_ + h*DH_ + c] : 0.f;
        Ks[r*KSTR+c] = f2bf(v);
    }
    // stage V transposed: Vts[dh][key] (32x320)
    for(int idx=tid; idx<KPV_*DH_; idx+=256){
        int r = idx>>5, c = idx&31;    // r=key, c=dh
        float v = (r<NQ_)? V[((size_t)(b*NQ_+r))*D_ + h*DH_ + c] : 0.f;
        Vts[c*VSTR+r] = f2bf(v);
    }
    // zero Ps padding cols [304,320)
    for(int idx=tid; idx<QT_*16; idx+=256){
        int r = idx>>4, c = idx&15;
        Ps[r*PSTR + 304 + c] = 0;
    }
    __syncthreads();

    int lane = tid&63, wave = tid>>6;
    int lr = lane&15, lq = lane>>4;
    int mrow = wave*16;   // wave's 16 q-rows within tile
    const float scale = 0.17677669529663687f;

    // ---- S = Q K^T : 19 n-tiles ----
    float4v acc[19];
    #pragma unroll
    for(int t=0;t<19;t++){ acc[t].x=0.f; acc[t].y=0.f; acc[t].z=0.f; acc[t].w=0.f; }
    short8 afrag = *(const short8*)(&Qs[(mrow+lr)*KSTR + lq*8]);
    #pragma unroll
    for(int t=0;t<19;t++){
        short8 bfrag = *(const short8*)(&Ks[(t*16+lr)*KSTR + lq*8]);
        acc[t] = __builtin_amdgcn_mfma_f32_16x16x32_bf16(afrag, bfrag, acc[t], 0,0,0);
    }
    // scale + mask padded keys (tile 18, col>=12 -> key>=300)
    #pragma unroll
    for(int t=0;t<19;t++){
        #pragma unroll
        for(int r=0;r<4;r++) acc[t][r] *= scale;
    }
    if(lr>=12){
        #pragma unroll
        for(int r=0;r<4;r++) acc[18][r] = -1e30f;
    }
    // row max (per reg r, across 16-lane group x 19 tiles)
    float mx[4];
    #pragma unroll
    for(int r=0;r<4;r++){
        float m = acc[0][r];
        #pragma unroll
        for(int t=1;t<19;t++) m = fmaxf(m, acc[t][r]);
        m = fmaxf(m, __shfl_xor(m,1));
        m = fmaxf(m, __shfl_xor(m,2));
        m = fmaxf(m, __shfl_xor(m,4));
        m = fmaxf(m, __shfl_xor(m,8));
        mx[r]=m;
    }
    // exp + row sum
    float sum[4] = {0.f,0.f,0.f,0.f};
    #pragma unroll
    for(int t=0;t<19;t++){
        #pragma unroll
        for(int r=0;r<4;r++){
            float p = __expf(acc[t][r]-mx[r]);
            acc[t][r]=p; sum[r]+=p;
        }
    }
    #pragma unroll
    for(int r=0;r<4;r++){
        float s = sum[r];
        s += __shfl_xor(s,1); s += __shfl_xor(s,2);
        s += __shfl_xor(s,4); s += __shfl_xor(s,8);
        sum[r] = 1.f/s;
    }
    // write P (bf16) to LDS
    #pragma unroll
    for(int t=0;t<19;t++){
        #pragma unroll
        for(int r=0;r<4;r++){
            Ps[(mrow + lq*4 + r)*PSTR + t*16 + lr] = f2bf(acc[t][r]*sum[r]);
        }
    }
    __syncthreads();
    // ---- O = P V : 10 k-chunks, 2 n-tiles (dh 0..15, 16..31) ----
    float4v oacc[2];
    oacc[0].x=0.f;oacc[0].y=0.f;oacc[0].z=0.f;oacc[0].w=0.f;
    oacc[1]=oacc[0];
    #pragma unroll
    for(int kc=0;kc<10;kc++){
        short8 pa = *(const short8*)(&Ps[(mrow+lr)*PSTR + kc*32 + lq*8]);
        #pragma unroll
        for(int n=0;n<2;n++){
            short8 vb = *(const short8*)(&Vts[(n*16+lr)*VSTR + kc*32 + lq*8]);
            oacc[n] = __builtin_amdgcn_mfma_f32_16x16x32_bf16(pa, vb, oacc[n], 0,0,0);
        }
    }
    #pragma unroll
    for(int n=0;n<2;n++){
        #pragma unroll
        for(int r=0;r<4;r++){
            int gq = q0 + mrow + lq*4 + r;
            if(gq<NQ_)
                O[((size_t)(b*NQ_+gq))*D_ + h*DH_ + n*16 + lr] = oacc[n][r];
        }
    }
}

// ============== batched weight transpose f32[K][N] -> bf16[N][K] ==============
struct TDesc { const float* src; size_t dst_off; int K, N, tile_base; };
struct TPack { TDesc d[12]; };

__global__ __launch_bounds__(256) void transpose_pack_kernel(TPack p, short* __restrict__ WT){
    int blk = blockIdx.x;
    int di = 0;
    for(int i=0;i<12;i++){ if(blk >= p.d[i].tile_base) di = i; }
    TDesc d = p.d[di];
    int rel = blk - d.tile_base;
    int ntx = (d.N+31)/32;
    int tn = (rel % ntx)*32, tk = (rel / ntx)*32;
    __shared__ float t[32][33];
    int tx = threadIdx.x&31, ty = threadIdx.x>>5;
    for(int i=0;i<32;i+=8){
        int k = tk+ty+i, n = tn+tx;
        t[ty+i][tx] = (k<d.K && n<d.N)? d.src[(size_t)k*d.N+n] : 0.f;
    }
    __syncthreads();
    short* out = WT + d.dst_off;
    for(int i=0;i<32;i+=8){
        int n = tn+ty+i, k = tk+tx;
        if(n<d.N && k<d.K) out[(size_t)n*d.K+k] = f2bf(t[tx][ty+i]);
    }
}

// ================= SIMT GEMM (tiny K/N) =================
template<bool RELU>
__global__ __launch_bounds__(256) void gemm_kernel(
    const float* __restrict__ A, const float* __restrict__ W,
    const float* __restrict__ bias, float* __restrict__ Cf,
    int M, int K, int N)
{
    __shared__ float As[16][68];
    __shared__ float Bs[16][68];
    int tid = threadIdx.x;
    int m0 = blockIdx.y*64, n0 = blockIdx.x*64;
    int tm = tid>>4, tn = tid&15;
    float acc[4][4] = {};
    int lam = tid>>2;
    int lak = (tid&3)*4;
    int lbk = tid>>4;
    int lbn = (tid&15)*4;
    for(int k0=0;k0<K;k0+=16){
        {
            int m = m0+lam;
            #pragma unroll
            for(int j=0;j<4;j++){
                int k = k0+lak+j;
                float v=0.f;
                if(m<M && k<K) v = A[(size_t)m*K+k];
                As[lak+j][lam]=v;
            }
        }
        {
            int k = k0+lbk;
            #pragma unroll
            for(int j=0;j<4;j++){
                int n = n0+lbn+j;
                float v=0.f;
                if(k<K && n<N) v = W[(size_t)k*N+n];
                Bs[lbk][lbn+j]=v;
            }
        }
        __syncthreads();
        #pragma unroll
        for(int kk=0;kk<16;kk++){
            float a[4], bb[4];
            #pragma unroll
            for(int i=0;i<4;i++) a[i]=As[kk][tm*4+i];
            #pragma unroll
            for(int j=0;j<4;j++) bb[j]=Bs[kk][tn*4+j];
            #pragma unroll
            for(int i=0;i<4;i++)
                #pragma unroll
                for(int j=0;j<4;j++) acc[i][j] += a[i]*bb[j];
        }
        __syncthreads();
    }
    #pragma unroll
    for(int i=0;i<4;i++){
        int m=m0+tm*4+i; if(m>=M) continue;
        #pragma unroll
        for(int j=0;j<4;j++){
            int n=n0+tn*4+j; if(n>=N) continue;
            float v = acc[i][j] + bias[n];
            if(RELU) v = fmaxf(v,0.f);
            Cf[(size_t)m*N+n]=v;
        }
    }
}

// ---------------- small elementwise kernels ----------------
__global__ void copy_kernel(const float* __restrict__ a, float* __restrict__ o, int n){
    int i = blockIdx.x*blockDim.x+threadIdx.x;
    if(i<n) o[i]=a[i];
}
__global__ void sigmoid_init_kernel(const float* __restrict__ a, float* __restrict__ o, int n){
    int i = blockIdx.x*blockDim.x+threadIdx.x;
    if(i<n){ float x=a[i]; o[i]=1.f/(1.f+expf(-x)); }
}
__global__ void add_kernel(const float* __restrict__ a, const float* __restrict__ b, float* __restrict__ c, int n){
    int i = blockIdx.x*blockDim.x+threadIdx.x;
    if(i<n) c[i]=a[i]+b[i];
}
__global__ void bbox_update_kernel(float* __restrict__ refd, const float* __restrict__ delta, int n){
    int i = blockIdx.x*blockDim.x+threadIdx.x;
    if(i>=n) return;
    float x = refd[i];
    x = fminf(fmaxf(x,0.f),1.f);
    float num = fmaxf(x,1e-5f), den = fmaxf(1.f-x,1e-5f);
    float nd = delta[i] + logf(num/den);
    refd[i] = 1.f/(1.f+expf(-nd));
}
__global__ void write_out_kernel(const float* __restrict__ refd, const float* __restrict__ logits, float* __restrict__ out){
    int i = blockIdx.x*blockDim.x+threadIdx.x;
    if(i<BN_*4) out[i]=refd[i];
    else if(i<BN_*4+BN_*NCLS_) out[i]=logits[i-BN_*4];
}

// ---------------- layernorm with residual ----------------
__global__ __launch_bounds__(256) void ln_residual_kernel(
    float* __restrict__ cur, const float* __restrict__ t2,
    const float* __restrict__ g, const float* __restrict__ b)
{
    int row = blockIdx.x; int c = threadIdx.x;
    size_t idx = (size_t)row*D_+c;
    float x = cur[idx] + t2[idx];
    float v1 = x, v2 = x*x;
    #pragma unroll
    for(int o=32;o>0;o>>=1){ v1 += __shfl_down(v1,o,64); v2 += __shfl_down(v2,o,64); }
    __shared__ float s1[4], s2[4], st[2];
    int wid=c>>6, lane=c&63;
    if(lane==0){ s1[wid]=v1; s2[wid]=v2; }
    __syncthreads();
    if(c==0){
        float a=0,d=0;
        #pragma unroll
        for(int i=0;i<4;i++){a+=s1[i]; d+=s2[i];}
        st[0]=a/(float)D_; st[1]=d/(float)D_;
    }
    __syncthreads();
    float m=st[0], var=st[1]-m*m;
    float y = (x-m)*rsqrtf(var+1e-5f)*g[c] + b[c];
    cur[idx]=y;
}

// ---------------- deform attw softmax ----------------
__global__ void attw_softmax_kernel(float* __restrict__ aw){
    int t = blockIdx.x*blockDim.x+threadIdx.x;
    if(t>=BN_*NHEAD_) return;
    int row=t/NHEAD_, h=t%NHEAD_;
    float* p = aw + (size_t)row*96 + h*12;
    float m=-1e30f;
    #pragma unroll
    for(int i=0;i<12;i++) m=fmaxf(m,p[i]);
    float e[12]; float s=0.f;
    #pragma unroll
    for(int i=0;i<12;i++){ e[i]=expf(p[i]-m); s+=e[i]; }
    float inv=1.f/s;
    #pragma unroll
    for(int i=0;i<12;i++) p[i]=e[i]*inv;
}

// ---------------- deformable sampling ----------------
__global__ __launch_bounds__(256) void deform_sample_kernel(
    const float* __restrict__ refd, const float* __restrict__ offs,
    const float* __restrict__ attw, const bf16* __restrict__ value,
    float* __restrict__ outacc)
{
    int row = blockIdx.x; int b = row/NQ_;
    int tid = threadIdx.x; int h = tid>>5, c = tid&31;
    __shared__ float so[192], sa[96], sr[4];
    if(tid<192) so[tid]=offs[(size_t)row*192+tid];
    if(tid<96)  sa[tid]=attw[(size_t)row*96+tid];
    if(tid<4)   sr[tid]=refd[(size_t)row*4+tid];
    __syncthreads();
    float cx=sr[0], cy=sr[1], rw=sr[2], rh=sr[3];
    const int HS[3]={80,40,20}, WS[3]={80,40,20}, ST[3]={0,6400,8000};
    float acc=0.f;
    const bf16* vb = value + (size_t)b*LM_*D_ + h*DH_ + c;
    for(int lv=0;lv<3;lv++){
        int Hl=HS[lv], Wl=WS[lv], st=ST[lv];
        #pragma unroll
        for(int pt=0;pt<4;pt++){
            int oi = ((h*3+lv)*4+pt)*2;
            float ox=so[oi], oy=so[oi+1];
            float wa=sa[h*12+lv*4+pt];
            float lx = cx + ox*0.25f*rw*0.5f;
            float ly = cy + oy*0.25f*rh*0.5f;
            float x = lx*(float)Wl - 0.5f, y = ly*(float)Hl - 0.5f;
            float x0f=floorf(x), y0f=floorf(y);
            float wx=x-x0f, wy=y-y0f;
            int x0=(int)x0f, y0=(int)y0f;
            #pragma unroll
            for(int dy=0;dy<2;dy++){
                #pragma unroll
                for(int dx=0;dx<2;dx++){
                    int xi=x0+dx, yi=y0+dy;
                    if(xi>=0 && xi<Wl && yi>=0 && yi<Hl){
                        float w = (dx? wx : 1.f-wx)*(dy? wy : 1.f-wy);
                        int lin = yi*Wl+xi;
                        acc += __bfloat162float(vb[(size_t)(st+lin)*D_]) * (w*wa);
                    }
                }
            }
        }
    }
    outacc[(size_t)row*D_+tid]=acc;
}

// ---------------- host helpers ----------------
static void gemm_simt(const float*A, const float*W, const float*b, float*C,
                      int M,int K,int N, hipStream_t s, bool relu){
    dim3 g((N+63)/64,(M+63)/64);
    if(relu) gemm_kernel<true><<<g,256,0,s>>>(A,W,b,C,M,K,N);
    else     gemm_kernel<false><<<g,256,0,s>>>(A,W,b,C,M,K,N);
}
static void mfma_gemm(const float*A, const short*WT, const float*b, void*C,
                      int M,int K,int N, hipStream_t s, bool relu, bool outbf16){
    dim3 g((N+127)/128,(M+127)/128);
    if(outbf16)      mfma_gemm_kernel<false,true ><<<g,256,0,s>>>(A,WT,b,C,M,K,N);
    else if(relu)    mfma_gemm_kernel<true ,false><<<g,256,0,s>>>(A,WT,b,C,M,K,N);
    else             mfma_gemm_kernel<false,false><<<g,256,0,s>>>(A,WT,b,C,M,K,N);
}
static int ntiles(int K,int N){ return ((N+31)/32)*((K+31)/32); }

extern "C" void kernel_launch(void* const* d_in, const int* in_sizes, int n_in,
                              void* d_out, int out_size, void* d_ws, size_t ws_size,
                              hipStream_t stream) {
    const float* tgt   = (const float*)d_in[0];
    const float* rpu   = (const float*)d_in[1];
    const float* mem   = (const float*)d_in[2];
    const float* sa_wq = (const float*)d_in[3];
    const float* sa_wk = (const float*)d_in[4];
    const float* sa_wv = (const float*)d_in[5];
    const float* sa_wo = (const float*)d_in[6];
    const float* val_w = (const float*)d_in[7];
    const float* out_w = (const float*)d_in[8];
    const float* bb_w1 = (const float*)d_in[9];
    const float* bb_w2 = (const float*)d_in[10];
    const float* sa_bq = (const float*)d_in[11];
    const float* sa_bk = (const float*)d_in[12];
    const float* sa_bv = (const float*)d_in[13];
    const float* sa_bo = (const float*)d_in[14];
    const float* ln1_b = (const float*)d_in[15];
    const float* ln2_b = (const float*)d_in[16];
    const float* ln3_b = (const float*)d_in[17];
    const float* val_b = (const float*)d_in[18];
    const float* out_b = (const float*)d_in[19];
    const float* ffn_b2= (const float*)d_in[20];
    const float* bb_b1 = (const float*)d_in[21];
    const float* bb_b2 = (const float*)d_in[22];
    const float* ln1_g = (const float*)d_in[23];
    const float* ln2_g = (const float*)d_in[24];
    const float* ln3_g = (const float*)d_in[25];
    const float* off_w = (const float*)d_in[26];
    const float* off_b = (const float*)d_in[27];
    const float* attw_w= (const float*)d_in[28];
    const float* attw_b= (const float*)d_in[29];
    const float* ffn_w1= (const float*)d_in[30];
    const float* ffn_b1= (const float*)d_in[31];
    const float* ffn_w2= (const float*)d_in[32];
    const float* bb_w3 = (const float*)d_in[33];
    const float* bb_b3 = (const float*)d_in[34];
    const float* sc_w  = (const float*)d_in[35];
    const float* sc_b  = (const float*)d_in[36];
    const float* qp_w1 = (const float*)d_in[37];
    const float* qp_b1 = (const float*)d_in[38];
    const float* qp_w2 = (const float*)d_in[39];
    const float* qp_b2 = (const float*)d_in[40];

    const size_t BND = (size_t)BN_*D_;
    float* ws = (float*)d_ws;
    float* cur    = ws;
    float* pos    = cur + BND;
    float* qbuf   = pos + BND;
    float* t2     = qbuf+ BND;
    float* tmp    = t2  + BND;
    float* Qh     = tmp + BND;
    float* Kh     = Qh  + BND;
    float* Vh     = Kh  + BND;
    float* offsb  = Vh  + BND;
    float* attwb  = offsb+ (size_t)BN_*192;
    float* refd   = attwb+ (size_t)BN_*96;
    float* delta  = refd + (size_t)BN_*4;
    float* logitsb= delta+ (size_t)BN_*4;
    float* U      = logitsb + (size_t)BN_*NCLS_;   // union region: 17.2M floats
    float* hid512 = U;
    bf16*  value  = (bf16*)U;
    float* ffnh   = U;
    float* bb1    = Qh;
    float* bb2    = Kh;
    short* WT     = (short*)(U + (size_t)17203200);
    const size_t oWQ=0, oWK=65536, oWV=131072, oWO=196608, oVAL=262144, oOUT=327680,
                 oOFF=393216, oATT=442368, oF1=466944, oF2=729088, oB1=991232, oB2=1056768;
    const size_t WT_LAYER_SZ = 1122304;
    short* qp2T = WT + WT_LAYER_SZ;            // 512x256
    short* scT  = qp2T + 131072;               // 80x256

    const int nBN_D = (int)BND;
    copy_kernel<<<(nBN_D+255)/256,256,0,stream>>>(tgt, cur, nBN_D);
    sigmoid_init_kernel<<<(BN_*4+255)/256,256,0,stream>>>(rpu, refd, BN_*4);

    {
        TPack tp; int base=0;
        tp.d[0] = { qp_w2, (size_t)0, 512, 256, base }; base += ntiles(512,256);
        tp.d[1] = { sc_w + (size_t)(NLAYERS_-1)*D_*NCLS_, (size_t)(scT-qp2T), 256, 80, base }; base += ntiles(256,80);
        for(int i=2;i<12;i++) tp.d[i] = { nullptr, 0, 0, 0, 0x7FFFFFFF };
        transpose_pack_kernel<<<base,256,0,stream>>>(tp, qp2T);
    }

    for(int i=0;i<NLAYERS_;i++){
        {
            TPack tp; int base=0;
            const float* srcs[12] = { sa_wq+(size_t)i*D_*D_, sa_wk+(size_t)i*D_*D_, sa_wv+(size_t)i*D_*D_,
                                      sa_wo+(size_t)i*D_*D_, val_w+(size_t)i*D_*D_, out_w+(size_t)i*D_*D_,
                                      off_w+(size_t)i*D_*192, attw_w+(size_t)i*D_*96,
                                      ffn_w1+(size_t)i*D_*DFF_, ffn_w2+(size_t)i*DFF_*D_,
                                      bb_w1+(size_t)i*D_*D_, bb_w2+(size_t)i*D_*D_ };
            const size_t offs[12] = { oWQ,oWK,oWV,oWO,oVAL,oOUT,oOFF,oATT,oF1,oF2,oB1,oB2 };
            const int Ks[12] = { 256,256,256,256,256,256,256,256,256,1024,256,256 };
            const int Ns[12] = { 256,256,256,256,256,256,192,96,1024,256,256,256 };
            for(int j=0;j<12;j++){
                tp.d[j] = { srcs[j], offs[j], Ks[j], Ns[j], base };
                base += ntiles(Ks[j],Ns[j]);
            }
            transpose_pack_kernel<<<base,256,0,stream>>>(tp, WT);
        }
        // pos = MLP2(refd)
        gemm_simt(refd, qp_w1, qp_b1, hid512, BN_, 4, 512, stream, true);
        mfma_gemm(hid512, qp2T, qp_b2, pos, BN_, 512, D_, stream, false, false);
        add_kernel<<<(nBN_D+255)/256,256,0,stream>>>(cur, pos, qbuf, nBN_D);
        // MHA
        mfma_gemm(qbuf, WT+oWQ, sa_bq+(size_t)i*D_, Qh, BN_, D_, D_, stream, false, false);
        mfma_gemm(qbuf, WT+oWK, sa_bk+(size_t)i*D_, Kh, BN_, D_, D_, stream, false, false);
        mfma_gemm(cur,  WT+oWV, sa_bv+(size_t)i*D_, Vh, BN_, D_, D_, stream, false, false);
        {
            dim3 g((NQ_+QT_-1)/QT_, BS_*NHEAD_);
            fused_mha_kernel<<<g,256,0,stream>>>(Qh, Kh, Vh, tmp);
        }
        mfma_gemm(tmp, WT+oWO, sa_bo+(size_t)i*D_, t2, BN_, D_, D_, stream, false, false);
        ln_residual_kernel<<<BN_,256,0,stream>>>(cur, t2, ln1_g+(size_t)i*D_, ln1_b+(size_t)i*D_);
        // deformable attention
        add_kernel<<<(nBN_D+255)/256,256,0,stream>>>(cur, pos, qbuf, nBN_D);
        mfma_gemm(mem, WT+oVAL, val_b+(size_t)i*D_, value, BS_*LM_, D_, D_, stream, false, true);
        mfma_gemm(qbuf, WT+oOFF, off_b+(size_t)i*192, offsb, BN_, D_, 192, stream, false, false);
        mfma_gemm(qbuf, WT+oATT, attw_b+(size_t)i*96, attwb, BN_, D_, 96, stream, false, false);
        attw_softmax_kernel<<<(BN_*NHEAD_+255)/256,256,0,stream>>>(attwb);
        deform_sample_kernel<<<BN_,256,0,stream>>>(refd, offsb, attwb, value, tmp);
        mfma_gemm(tmp, WT+oOUT, out_b+(size_t)i*D_, t2, BN_, D_, D_, stream, false, false);
        ln_residual_kernel<<<BN_,256,0,stream>>>(cur, t2, ln2_g+(size_t)i*D_, ln2_b+(size_t)i*D_);
        // FFN
        mfma_gemm(cur, WT+oF1, ffn_b1+(size_t)i*DFF_, ffnh, BN_, D_, DFF_, stream, true, false);
        mfma_gemm(ffnh, WT+oF2, ffn_b2+(size_t)i*D_, t2, BN_, DFF_, D_, stream, false, false);
        ln_residual_kernel<<<BN_,256,0,stream>>>(cur, t2, ln3_g+(size_t)i*D_, ln3_b+(size_t)i*D_);
        // bbox head
        mfma_gemm(cur, WT+oB1, bb_b1+(size_t)i*D_, bb1, BN_, D_, D_, stream, true, false);
        mfma_gemm(bb1, WT+oB2, bb_b2+(size_t)i*D_, bb2, BN_, D_, D_, stream, true, false);
        gemm_simt(bb2, bb_w3+(size_t)i*D_*4, bb_b3+(size_t)i*4, delta, BN_, D_, 4, stream, false);
        bbox_update_kernel<<<(BN_*4+255)/256,256,0,stream>>>(refd, delta, BN_*4);
    }
    mfma_gemm(cur, scT, sc_b+(size_t)(NLAYERS_-1)*NCLS_, logitsb, BN_, D_, NCLS_, stream, false, false);
    int tot = BN_*4 + BN_*NCLS_;
    write_out_kernel<<<(tot+255)/256,256,0,stream>>>(refd, logitsb, (float*)d_out);
}

// Round 5
// 4139.846 us; speedup vs baseline: 2.0483x; 1.0837x over previous
//
#include <hip/hip_runtime.h>
#include <hip/hip_bf16.h>

typedef __hip_bfloat16 bf16;
typedef short short8 __attribute__((ext_vector_type(8)));
typedef short short4v __attribute__((ext_vector_type(4)));
typedef float float4v __attribute__((ext_vector_type(4)));

#define D_ 256
#define NHEAD_ 8
#define DH_ 32
#define NQ_ 300
#define NLAYERS_ 6
#define DFF_ 1024
#define NCLS_ 80
#define BS_ 16
#define LM_ 8400
#define BN_ (BS_*NQ_)   // 4800

static __device__ __forceinline__ short f2bf(float x){
    union{float f; unsigned u;} v; v.f = x;
    unsigned r = v.u + 0x7FFF + ((v.u>>16)&1);
    return (short)(r>>16);
}

// ================= MFMA bf16 GEMM: C = act(A@W + bias) =================
// A: (M,K) f32 or bf16 ; WT: (N,K) bf16 ; bias split at nsplit ; C: f32 or bf16
#define LSTR 40   // LDS row stride in bf16 elems (80 B)

template<bool ABF16, bool RELU, bool OUTBF16>
__global__ __launch_bounds__(256) void mfma_gemm_kernel(
    const void* __restrict__ Av, const short* __restrict__ WT,
    const float* __restrict__ bias0, const float* __restrict__ bias1, int nsplit,
    void* __restrict__ Cv, int M, int K, int N)
{
    __shared__ short As[128*LSTR];
    __shared__ short Bs[128*LSTR];
    int tid = threadIdx.x;
    int lane = tid&63, wave = tid>>6;
    int m0 = blockIdx.y*128, n0 = blockIdx.x*128;
    int wm = (wave>>1)*64, wn = (wave&1)*64;
    int lr = lane&15, lq = lane>>4;
    float4v acc[4][4];
    #pragma unroll
    for(int i=0;i<4;i++)
        #pragma unroll
        for(int j=0;j<4;j++){ acc[i][j].x=0.f; acc[i][j].y=0.f; acc[i][j].z=0.f; acc[i][j].w=0.f; }

    for(int k0=0;k0<K;k0+=32){
        if(ABF16){
            const short* Ah = (const short*)Av;
            #pragma unroll
            for(int it=0; it<2; ++it){
                int idx = (it*256+tid)*8;
                int r = idx>>5, kk = idx&31;
                int gm = m0+r;
                short8 v = {};
                if(gm<M) v = *(const short8*)(Ah + (size_t)gm*K + (k0+kk));
                *(short8*)(&As[r*LSTR+kk]) = v;
            }
        } else {
            const float* Af = (const float*)Av;
            #pragma unroll
            for(int it=0; it<4; ++it){
                int idx = (it*256+tid)*4;
                int r = idx>>5, kk = idx&31;
                int gm = m0+r;
                float4v v; v.x=0.f;v.y=0.f;v.z=0.f;v.w=0.f;
                if(gm<M) v = *(const float4v*)(Af + (size_t)gm*K + (k0+kk));
                short4v h; h.x=f2bf(v.x); h.y=f2bf(v.y); h.z=f2bf(v.z); h.w=f2bf(v.w);
                *(short4v*)(&As[r*LSTR+kk]) = h;
            }
        }
        #pragma unroll
        for(int it=0; it<2; ++it){
            int idx = (it*256+tid)*8;
            int r = idx>>5, kk = idx&31;
            int gn = n0+r;
            short8 v = {};
            if(gn<N) v = *(const short8*)(WT + (size_t)gn*K + (k0+kk));
            *(short8*)(&Bs[r*LSTR+kk]) = v;
        }
        __syncthreads();
        short8 af[4], bfr[4];
        #pragma unroll
        for(int mi=0;mi<4;mi++) af[mi]  = *(const short8*)(&As[(wm+mi*16+lr)*LSTR + lq*8]);
        #pragma unroll
        for(int ni=0;ni<4;ni++) bfr[ni] = *(const short8*)(&Bs[(wn+ni*16+lr)*LSTR + lq*8]);
        #pragma unroll
        for(int mi=0;mi<4;mi++)
            #pragma unroll
            for(int ni=0;ni<4;ni++)
                acc[mi][ni] = __builtin_amdgcn_mfma_f32_16x16x32_bf16(af[mi], bfr[ni], acc[mi][ni], 0,0,0);
        __syncthreads();
    }
    float* Cf=(float*)Cv; bf16* Ch=(bf16*)Cv;
    #pragma unroll
    for(int mi=0;mi<4;mi++){
        #pragma unroll
        for(int r=0;r<4;r++){
            int gm = m0+wm+mi*16+lq*4+r;
            if(gm>=M) continue;
            #pragma unroll
            for(int ni=0;ni<4;ni++){
                int gn = n0+wn+ni*16+lr;
                if(gn>=N) continue;
                float bv = (gn<nsplit)? bias0[gn] : bias1[gn-nsplit];
                float v = acc[mi][ni][r] + bv;
                if(RELU) v = fmaxf(v,0.f);
                if(OUTBF16) Ch[(size_t)gm*N+gn]=__float2bfloat16(v);
                else        Cf[(size_t)gm*N+gn]=v;
            }
        }
    }
}

// ================= fused MHA: S=QK^T, softmax, O=PV (per b,h,qtile) =================
#define QT_  64
#define KP_  304
#define KPV_ 320
#define KSTR 36
#define VSTR 324
#define PSTR 324

__global__ __launch_bounds__(256) void fused_mha_kernel(
    const float* __restrict__ Q, const float* __restrict__ K, int ldq,
    const float* __restrict__ V, float* __restrict__ O)
{
    int bh = blockIdx.y; int b = bh>>3, h = bh&7;
    int q0 = blockIdx.x*QT_;
    __shared__ short Qs[QT_*KSTR];
    __shared__ short Ks[KP_*KSTR];
    __shared__ short Vts[DH_*VSTR];
    __shared__ short Ps[QT_*PSTR];
    int tid = threadIdx.x;
    for(int idx=tid; idx<QT_*DH_; idx+=256){
        int r = idx>>5, c = idx&31;
        int gq = q0+r;
        float v = (gq<NQ_)? Q[((size_t)(b*NQ_+gq))*ldq + h*DH_ + c] : 0.f;
        Qs[r*KSTR+c] = f2bf(v);
    }
    for(int idx=tid; idx<KP_*DH_; idx+=256){
        int r = idx>>5, c = idx&31;
        float v = (r<NQ_)? K[((size_t)(b*NQ_+r))*ldq + h*DH_ + c] : 0.f;
        Ks[r*KSTR+c] = f2bf(v);
    }
    for(int idx=tid; idx<KPV_*DH_; idx+=256){
        int r = idx>>5, c = idx&31;
        float v = (r<NQ_)? V[((size_t)(b*NQ_+r))*D_ + h*DH_ + c] : 0.f;
        Vts[c*VSTR+r] = f2bf(v);
    }
    for(int idx=tid; idx<QT_*16; idx+=256){
        int r = idx>>4, c = idx&15;
        Ps[r*PSTR + 304 + c] = 0;
    }
    __syncthreads();

    int lane = tid&63, wave = tid>>6;
    int lr = lane&15, lq = lane>>4;
    int mrow = wave*16;
    const float scale = 0.17677669529663687f;

    float4v acc[19];
    #pragma unroll
    for(int t=0;t<19;t++){ acc[t].x=0.f; acc[t].y=0.f; acc[t].z=0.f; acc[t].w=0.f; }
    short8 afrag = *(const short8*)(&Qs[(mrow+lr)*KSTR + lq*8]);
    #pragma unroll
    for(int t=0;t<19;t++){
        short8 bfrag = *(const short8*)(&Ks[(t*16+lr)*KSTR + lq*8]);
        acc[t] = __builtin_amdgcn_mfma_f32_16x16x32_bf16(afrag, bfrag, acc[t], 0,0,0);
    }
    #pragma unroll
    for(int t=0;t<19;t++){
        #pragma unroll
        for(int r=0;r<4;r++) acc[t][r] *= scale;
    }
    if(lr>=12){
        #pragma unroll
        for(int r=0;r<4;r++) acc[18][r] = -1e30f;
    }
    float mx[4];
    #pragma unroll
    for(int r=0;r<4;r++){
        float m = acc[0][r];
        #pragma unroll
        for(int t=1;t<19;t++) m = fmaxf(m, acc[t][r]);
        m = fmaxf(m, __shfl_xor(m,1));
        m = fmaxf(m, __shfl_xor(m,2));
        m = fmaxf(m, __shfl_xor(m,4));
        m = fmaxf(m, __shfl_xor(m,8));
        mx[r]=m;
    }
    float sum[4] = {0.f,0.f,0.f,0.f};
    #pragma unroll
    for(int t=0;t<19;t++){
        #pragma unroll
        for(int r=0;r<4;r++){
            float p = __expf(acc[t][r]-mx[r]);
            acc[t][r]=p; sum[r]+=p;
        }
    }
    #pragma unroll
    for(int r=0;r<4;r++){
        float s = sum[r];
        s += __shfl_xor(s,1); s += __shfl_xor(s,2);
        s += __shfl_xor(s,4); s += __shfl_xor(s,8);
        sum[r] = 1.f/s;
    }
    #pragma unroll
    for(int t=0;t<19;t++){
        #pragma unroll
        for(int r=0;r<4;r++){
            Ps[(mrow + lq*4 + r)*PSTR + t*16 + lr] = f2bf(acc[t][r]*sum[r]);
        }
    }
    __syncthreads();
    float4v oacc[2];
    oacc[0].x=0.f;oacc[0].y=0.f;oacc[0].z=0.f;oacc[0].w=0.f;
    oacc[1]=oacc[0];
    #pragma unroll
    for(int kc=0;kc<10;kc++){
        short8 pa = *(const short8*)(&Ps[(mrow+lr)*PSTR + kc*32 + lq*8]);
        #pragma unroll
        for(int n=0;n<2;n++){
            short8 vb = *(const short8*)(&Vts[(n*16+lr)*VSTR + kc*32 + lq*8]);
            oacc[n] = __builtin_amdgcn_mfma_f32_16x16x32_bf16(pa, vb, oacc[n], 0,0,0);
        }
    }
    #pragma unroll
    for(int n=0;n<2;n++){
        #pragma unroll
        for(int r=0;r<4;r++){
            int gq = q0 + mrow + lq*4 + r;
            if(gq<NQ_)
                O[((size_t)(b*NQ_+gq))*D_ + h*DH_ + n*16 + lr] = oacc[n][r];
        }
    }
}

// ============== batched weight transpose f32[K][N] -> bf16[N][K] ==============
struct TDesc { const float* src; size_t dst_off; int K, N, tile_base; };
struct TPack { TDesc d[12]; };

__global__ __launch_bounds__(256) void transpose_pack_kernel(TPack p, short* __restrict__ WT){
    int blk = blockIdx.x;
    int di = 0;
    for(int i=0;i<12;i++){ if(blk >= p.d[i].tile_base) di = i; }
    TDesc d = p.d[di];
    int rel = blk - d.tile_base;
    int ntx = (d.N+31)/32;
    int tn = (rel % ntx)*32, tk = (rel / ntx)*32;
    __shared__ float t[32][33];
    int tx = threadIdx.x&31, ty = threadIdx.x>>5;
    for(int i=0;i<32;i+=8){
        int k = tk+ty+i, n = tn+tx;
        t[ty+i][tx] = (k<d.K && n<d.N)? d.src[(size_t)k*d.N+n] : 0.f;
    }
    __syncthreads();
    short* out = WT + d.dst_off;
    for(int i=0;i<32;i+=8){
        int n = tn+ty+i, k = tk+tx;
        if(n<d.N && k<d.K) out[(size_t)n*d.K+k] = f2bf(t[tx][ty+i]);
    }
}

// ================= SIMT GEMM (tiny K/N) =================
template<bool RELU>
__global__ __launch_bounds__(256) void gemm_kernel(
    const float* __restrict__ A, const float* __restrict__ W,
    const float* __restrict__ bias, float* __restrict__ Cf,
    int M, int K, int N)
{
    __shared__ float As[16][68];
    __shared__ float Bs[16][68];
    int tid = threadIdx.x;
    int m0 = blockIdx.y*64, n0 = blockIdx.x*64;
    int tm = tid>>4, tn = tid&15;
    float acc[4][4] = {};
    int lam = tid>>2;
    int lak = (tid&3)*4;
    int lbk = tid>>4;
    int lbn = (tid&15)*4;
    for(int k0=0;k0<K;k0+=16){
        {
            int m = m0+lam;
            #pragma unroll
            for(int j=0;j<4;j++){
                int k = k0+lak+j;
                float v=0.f;
                if(m<M && k<K) v = A[(size_t)m*K+k];
                As[lak+j][lam]=v;
            }
        }
        {
            int k = k0+lbk;
            #pragma unroll
            for(int j=0;j<4;j++){
                int n = n0+lbn+j;
                float v=0.f;
                if(k<K && n<N) v = W[(size_t)k*N+n];
                Bs[lbk][lbn+j]=v;
            }
        }
        __syncthreads();
        #pragma unroll
        for(int kk=0;kk<16;kk++){
            float a[4], bb[4];
            #pragma unroll
            for(int i=0;i<4;i++) a[i]=As[kk][tm*4+i];
            #pragma unroll
            for(int j=0;j<4;j++) bb[j]=Bs[kk][tn*4+j];
            #pragma unroll
            for(int i=0;i<4;i++)
                #pragma unroll
                for(int j=0;j<4;j++) acc[i][j] += a[i]*bb[j];
        }
        __syncthreads();
    }
    #pragma unroll
    for(int i=0;i<4;i++){
        int m=m0+tm*4+i; if(m>=M) continue;
        #pragma unroll
        for(int j=0;j<4;j++){
            int n=n0+tn*4+j; if(n>=N) continue;
            float v = acc[i][j] + bias[n];
            if(RELU) v = fmaxf(v,0.f);
            Cf[(size_t)m*N+n]=v;
        }
    }
}

// ---------------- small elementwise kernels ----------------
__global__ void copy_kernel(const float* __restrict__ a, float* __restrict__ o, int n){
    int i = blockIdx.x*blockDim.x+threadIdx.x;
    if(i<n) o[i]=a[i];
}
__global__ void cvt_f32_bf16_kernel(const float* __restrict__ a, short* __restrict__ o, int n4){
    int i = blockIdx.x*blockDim.x+threadIdx.x;
    if(i<n4){
        float4v v = *(const float4v*)(a + (size_t)i*4);
        short4v h; h.x=f2bf(v.x); h.y=f2bf(v.y); h.z=f2bf(v.z); h.w=f2bf(v.w);
        *(short4v*)(o + (size_t)i*4) = h;
    }
}
__global__ void sigmoid_init_kernel(const float* __restrict__ a, float* __restrict__ o, int n){
    int i = blockIdx.x*blockDim.x+threadIdx.x;
    if(i<n){ float x=a[i]; o[i]=1.f/(1.f+expf(-x)); }
}
__global__ void add_kernel(const float* __restrict__ a, const float* __restrict__ b, float* __restrict__ c, int n){
    int i = blockIdx.x*blockDim.x+threadIdx.x;
    if(i<n) c[i]=a[i]+b[i];
}
__global__ void bbox_update_kernel(float* __restrict__ refd, const float* __restrict__ delta, int n){
    int i = blockIdx.x*blockDim.x+threadIdx.x;
    if(i>=n) return;
    float x = refd[i];
    x = fminf(fmaxf(x,0.f),1.f);
    float num = fmaxf(x,1e-5f), den = fmaxf(1.f-x,1e-5f);
    float nd = delta[i] + logf(num/den);
    refd[i] = 1.f/(1.f+expf(-nd));
}
__global__ void write_out_kernel(const float* __restrict__ refd, const float* __restrict__ logits, float* __restrict__ out){
    int i = blockIdx.x*blockDim.x+threadIdx.x;
    if(i<BN_*4) out[i]=refd[i];
    else if(i<BN_*4+BN_*NCLS_) out[i]=logits[i-BN_*4];
}

// ---------------- layernorm with residual ----------------
__global__ __launch_bounds__(256) void ln_residual_kernel(
    float* __restrict__ cur, const float* __restrict__ t2,
    const float* __restrict__ g, const float* __restrict__ b)
{
    int row = blockIdx.x; int c = threadIdx.x;
    size_t idx = (size_t)row*D_+c;
    float x = cur[idx] + t2[idx];
    float v1 = x, v2 = x*x;
    #pragma unroll
    for(int o=32;o>0;o>>=1){ v1 += __shfl_down(v1,o,64); v2 += __shfl_down(v2,o,64); }
    __shared__ float s1[4], s2[4], st[2];
    int wid=c>>6, lane=c&63;
    if(lane==0){ s1[wid]=v1; s2[wid]=v2; }
    __syncthreads();
    if(c==0){
        float a=0,d=0;
        #pragma unroll
        for(int i=0;i<4;i++){a+=s1[i]; d+=s2[i];}
        st[0]=a/(float)D_; st[1]=d/(float)D_;
    }
    __syncthreads();
    float m=st[0], var=st[1]-m*m;
    float y = (x-m)*rsqrtf(var+1e-5f)*g[c] + b[c];
    cur[idx]=y;
}

// ---------------- deform attw softmax (operates on fused off|attw buffer, stride 288) ----------------
__global__ void attw_softmax_kernel(float* __restrict__ oab){
    int t = blockIdx.x*blockDim.x+threadIdx.x;
    if(t>=BN_*NHEAD_) return;
    int row=t/NHEAD_, h=t%NHEAD_;
    float* p = oab + (size_t)row*288 + 192 + h*12;
    float m=-1e30f;
    #pragma unroll
    for(int i=0;i<12;i++) m=fmaxf(m,p[i]);
    float e[12]; float s=0.f;
    #pragma unroll
    for(int i=0;i<12;i++){ e[i]=__expf(p[i]-m); s+=e[i]; }
    float inv=1.f/s;
    #pragma unroll
    for(int i=0;i<12;i++) p[i]=e[i]*inv;
}

// ---------------- deformable sampling (fused off|attw buffer, stride 288) ----------------
__global__ __launch_bounds__(256) void deform_sample_kernel(
    const float* __restrict__ refd, const float* __restrict__ oab,
    const bf16* __restrict__ value, float* __restrict__ outacc)
{
    int row = blockIdx.x; int b = row/NQ_;
    int tid = threadIdx.x; int h = tid>>5, c = tid&31;
    __shared__ float so[192], sa[96], sr[4];
    if(tid<192) so[tid]=oab[(size_t)row*288+tid];
    if(tid<96)  sa[tid]=oab[(size_t)row*288+192+tid];
    if(tid<4)   sr[tid]=refd[(size_t)row*4+tid];
    __syncthreads();
    float cx=sr[0], cy=sr[1], rw=sr[2], rh=sr[3];
    const int HS[3]={80,40,20}, WS[3]={80,40,20}, ST[3]={0,6400,8000};
    float acc=0.f;
    const bf16* vb = value + (size_t)b*LM_*D_ + h*DH_ + c;
    for(int lv=0;lv<3;lv++){
        int Hl=HS[lv], Wl=WS[lv], st=ST[lv];
        #pragma unroll
        for(int pt=0;pt<4;pt++){
            int oi = ((h*3+lv)*4+pt)*2;
            float ox=so[oi], oy=so[oi+1];
            float wa=sa[h*12+lv*4+pt];
            float lx = cx + ox*0.25f*rw*0.5f;
            float ly = cy + oy*0.25f*rh*0.5f;
            float x = lx*(float)Wl - 0.5f, y = ly*(float)Hl - 0.5f;
            float x0f=floorf(x), y0f=floorf(y);
            float wx=x-x0f, wy=y-y0f;
            int x0=(int)x0f, y0=(int)y0f;
            #pragma unroll
            for(int dy=0;dy<2;dy++){
                #pragma unroll
                for(int dx=0;dx<2;dx++){
                    int xi=x0+dx, yi=y0+dy;
                    if(xi>=0 && xi<Wl && yi>=0 && yi<Hl){
                        float w = (dx? wx : 1.f-wx)*(dy? wy : 1.f-wy);
                        int lin = yi*Wl+xi;
                        acc += __bfloat162float(vb[(size_t)(st+lin)*D_]) * (w*wa);
                    }
                }
            }
        }
    }
    outacc[(size_t)row*D_+tid]=acc;
}

// ---------------- host helpers ----------------
static void gemm_simt(const float*A, const float*W, const float*b, float*C,
                      int M,int K,int N, hipStream_t s, bool relu){
    dim3 g((N+63)/64,(M+63)/64);
    if(relu) gemm_kernel<true><<<g,256,0,s>>>(A,W,b,C,M,K,N);
    else     gemm_kernel<false><<<g,256,0,s>>>(A,W,b,C,M,K,N);
}
static void mfma_gemm2(const void*A, bool abf16, const short*WT,
                       const float*b0, const float*b1, int nsplit, void*C,
                       int M,int K,int N, hipStream_t s, bool relu, bool outbf16){
    dim3 g((N+127)/128,(M+127)/128);
    if(abf16){
        if(outbf16) mfma_gemm_kernel<true,false,true ><<<g,256,0,s>>>(A,WT,b0,b1,nsplit,C,M,K,N);
        else        mfma_gemm_kernel<true,false,false><<<g,256,0,s>>>(A,WT,b0,b1,nsplit,C,M,K,N);
    } else {
        if(outbf16)      mfma_gemm_kernel<false,false,true ><<<g,256,0,s>>>(A,WT,b0,b1,nsplit,C,M,K,N);
        else if(relu)    mfma_gemm_kernel<false,true ,false><<<g,256,0,s>>>(A,WT,b0,b1,nsplit,C,M,K,N);
        else             mfma_gemm_kernel<false,false,false><<<g,256,0,s>>>(A,WT,b0,b1,nsplit,C,M,K,N);
    }
}
static void mfma_gemm(const float*A, const short*WT, const float*b, void*C,
                      int M,int K,int N, hipStream_t s, bool relu, bool outbf16){
    mfma_gemm2(A,false,WT,b,b,N,C,M,K,N,s,relu,outbf16);
}
static int ntiles(int K,int N){ return ((N+31)/32)*((K+31)/32); }

extern "C" void kernel_launch(void* const* d_in, const int* in_sizes, int n_in,
                              void* d_out, int out_size, void* d_ws, size_t ws_size,
                              hipStream_t stream) {
    const float* tgt   = (const float*)d_in[0];
    const float* rpu   = (const float*)d_in[1];
    const float* mem   = (const float*)d_in[2];
    const float* sa_wq = (const float*)d_in[3];
    const float* sa_wk = (const float*)d_in[4];
    const float* sa_wv = (const float*)d_in[5];
    const float* sa_wo = (const float*)d_in[6];
    const float* val_w = (const float*)d_in[7];
    const float* out_w = (const float*)d_in[8];
    const float* bb_w1 = (const float*)d_in[9];
    const float* bb_w2 = (const float*)d_in[10];
    const float* sa_bq = (const float*)d_in[11];
    const float* sa_bk = (const float*)d_in[12];
    const float* sa_bv = (const float*)d_in[13];
    const float* sa_bo = (const float*)d_in[14];
    const float* ln1_b = (const float*)d_in[15];
    const float* ln2_b = (const float*)d_in[16];
    const float* ln3_b = (const float*)d_in[17];
    const float* val_b = (const float*)d_in[18];
    const float* out_b = (const float*)d_in[19];
    const float* ffn_b2= (const float*)d_in[20];
    const float* bb_b1 = (const float*)d_in[21];
    const float* bb_b2 = (const float*)d_in[22];
    const float* ln1_g = (const float*)d_in[23];
    const float* ln2_g = (const float*)d_in[24];
    const float* ln3_g = (const float*)d_in[25];
    const float* off_w = (const float*)d_in[26];
    const float* off_b = (const float*)d_in[27];
    const float* attw_w= (const float*)d_in[28];
    const float* attw_b= (const float*)d_in[29];
    const float* ffn_w1= (const float*)d_in[30];
    const float* ffn_b1= (const float*)d_in[31];
    const float* ffn_w2= (const float*)d_in[32];
    const float* bb_w3 = (const float*)d_in[33];
    const float* bb_b3 = (const float*)d_in[34];
    const float* sc_w  = (const float*)d_in[35];
    const float* sc_b  = (const float*)d_in[36];
    const float* qp_w1 = (const float*)d_in[37];
    const float* qp_b1 = (const float*)d_in[38];
    const float* qp_w2 = (const float*)d_in[39];
    const float* qp_b2 = (const float*)d_in[40];

    const size_t BND = (size_t)BN_*D_;
    float* ws = (float*)d_ws;
    float* cur    = ws;
    float* pos    = cur + BND;
    float* qbuf   = pos + BND;
    float* t2     = qbuf+ BND;
    float* tmp    = t2  + BND;
    float* QKh    = tmp + BND;          // BN x 512 (Q | K)
    float* Vh     = QKh + 2*BND;
    float* offsb  = Vh  + BND;          // BN x 288 fused (off | attw)
    float* refd   = offsb+ (size_t)BN_*288;
    float* delta  = refd + (size_t)BN_*4;
    float* logitsb= delta+ (size_t)BN_*4;
    float* U      = logitsb + (size_t)BN_*NCLS_;   // union region: 17.2M floats
    float* hid512 = U;
    bf16*  value  = (bf16*)U;
    float* ffnh   = U;
    float* bb1    = QKh;
    float* bb2    = QKh + BND;
    short* WT     = (short*)(U + (size_t)17203200);
    const size_t oWQ=0, oWK=65536, oWV=131072, oWO=196608, oVAL=262144, oOUT=327680,
                 oOFF=393216, oATT=442368, oF1=466944, oF2=729088, oB1=991232, oB2=1056768;
    const size_t WT_LAYER_SZ = 1122304;
    short* qp2T = WT + WT_LAYER_SZ;            // 512x256
    short* scT  = qp2T + 131072;               // 80x256
    short* memT = scT + 20480;                 // bf16 copy of memory (34,406,400 shorts)
    // bytes needed incl. memT:
    const size_t NEED_MEMT = ((size_t)(memT - (short*)d_ws))*2 + (size_t)BS_*LM_*D_*2;
    const bool useB = ws_size >= NEED_MEMT;

    const int nBN_D = (int)BND;
    copy_kernel<<<(nBN_D+255)/256,256,0,stream>>>(tgt, cur, nBN_D);
    sigmoid_init_kernel<<<(BN_*4+255)/256,256,0,stream>>>(rpu, refd, BN_*4);
    if(useB){
        int n4 = BS_*LM_*D_/4;
        cvt_f32_bf16_kernel<<<(n4+255)/256,256,0,stream>>>(mem, memT, n4);
    }

    {
        TPack tp; int base=0;
        tp.d[0] = { qp_w2, (size_t)0, 512, 256, base }; base += ntiles(512,256);
        tp.d[1] = { sc_w + (size_t)(NLAYERS_-1)*D_*NCLS_, (size_t)(scT-qp2T), 256, 80, base }; base += ntiles(256,80);
        for(int i=2;i<12;i++) tp.d[i] = { nullptr, 0, 0, 0, 0x7FFFFFFF };
        transpose_pack_kernel<<<base,256,0,stream>>>(tp, qp2T);
    }

    for(int i=0;i<NLAYERS_;i++){
        {
            TPack tp; int base=0;
            const float* srcs[12] = { sa_wq+(size_t)i*D_*D_, sa_wk+(size_t)i*D_*D_, sa_wv+(size_t)i*D_*D_,
                                      sa_wo+(size_t)i*D_*D_, val_w+(size_t)i*D_*D_, out_w+(size_t)i*D_*D_,
                                      off_w+(size_t)i*D_*192, attw_w+(size_t)i*D_*96,
                                      ffn_w1+(size_t)i*D_*DFF_, ffn_w2+(size_t)i*DFF_*D_,
                                      bb_w1+(size_t)i*D_*D_, bb_w2+(size_t)i*D_*D_ };
            const size_t offs[12] = { oWQ,oWK,oWV,oWO,oVAL,oOUT,oOFF,oATT,oF1,oF2,oB1,oB2 };
            const int Ks[12] = { 256,256,256,256,256,256,256,256,256,1024,256,256 };
            const int Ns[12] = { 256,256,256,256,256,256,192,96,1024,256,256,256 };
            for(int j=0;j<12;j++){
                tp.d[j] = { srcs[j], offs[j], Ks[j], Ns[j], base };
                base += ntiles(Ks[j],Ns[j]);
            }
            transpose_pack_kernel<<<base,256,0,stream>>>(tp, WT);
        }
        // pos = MLP2(refd)
        gemm_simt(refd, qp_w1, qp_b1, hid512, BN_, 4, 512, stream, true);
        mfma_gemm(hid512, qp2T, qp_b2, pos, BN_, 512, D_, stream, false, false);
        add_kernel<<<(nBN_D+255)/256,256,0,stream>>>(cur, pos, qbuf, nBN_D);
        // MHA: fused Q|K projection (N=512), V projection, fused attention
        mfma_gemm2(qbuf, false, WT+oWQ, sa_bq+(size_t)i*D_, sa_bk+(size_t)i*D_, D_,
                   QKh, BN_, D_, 512, stream, false, false);
        mfma_gemm(cur,  WT+oWV, sa_bv+(size_t)i*D_, Vh, BN_, D_, D_, stream, false, false);
        {
            dim3 g((NQ_+QT_-1)/QT_, BS_*NHEAD_);
            fused_mha_kernel<<<g,256,0,stream>>>(QKh, QKh+256, 512, Vh, tmp);
        }
        mfma_gemm(tmp, WT+oWO, sa_bo+(size_t)i*D_, t2, BN_, D_, D_, stream, false, false);
        ln_residual_kernel<<<BN_,256,0,stream>>>(cur, t2, ln1_g+(size_t)i*D_, ln1_b+(size_t)i*D_);
        // deformable attention
        add_kernel<<<(nBN_D+255)/256,256,0,stream>>>(cur, pos, qbuf, nBN_D);
        if(useB) mfma_gemm2(memT, true, WT+oVAL, val_b+(size_t)i*D_, val_b+(size_t)i*D_, D_,
                            value, BS_*LM_, D_, D_, stream, false, true);
        else     mfma_gemm(mem, WT+oVAL, val_b+(size_t)i*D_, value, BS_*LM_, D_, D_, stream, false, true);
        // fused off|attw projection (N=288)
        mfma_gemm2(qbuf, false, WT+oOFF, off_b+(size_t)i*192, attw_b+(size_t)i*96, 192,
                   offsb, BN_, D_, 288, stream, false, false);
        attw_softmax_kernel<<<(BN_*NHEAD_+255)/256,256,0,stream>>>(offsb);
        deform_sample_kernel<<<BN_,256,0,stream>>>(refd, offsb, value, tmp);
        mfma_gemm(tmp, WT+oOUT, out_b+(size_t)i*D_, t2, BN_, D_, D_, stream, false, false);
        ln_residual_kernel<<<BN_,256,0,stream>>>(cur, t2, ln2_g+(size_t)i*D_, ln2_b+(size_t)i*D_);
        // FFN
        mfma_gemm(cur, WT+oF1, ffn_b1+(size_t)i*DFF_, ffnh, BN_, D_, DFF_, stream, true, false);
        mfma_gemm(ffnh, WT+oF2, ffn_b2+(size_t)i*D_, t2, BN_, DFF_, D_, stream, false, false);
        ln_residual_kernel<<<BN_,256,0,stream>>>(cur, t2, ln3_g+(size_t)i*D_, ln3_b+(size_t)i*D_);
        // bbox head
        mfma_gemm(cur, WT+oB1, bb_b1+(size_t)i*D_, bb1, BN_, D_, D_, stream, true, false);
        mfma_gemm(bb1, WT+oB2, bb_b2+(size_t)i*D_, bb2, BN_, D_, D_, stream, true, false);
        gemm_simt(bb2, bb_w3+(size_t)i*D_*4, bb_b3+(size_t)i*4, delta, BN_, D_, 4, stream, false);
        bbox_update_kernel<<<(BN_*4+255)/256,256,0,stream>>>(refd, delta, BN_*4);
    }
    mfma_gemm(cur, scT, sc_b+(size_t)(NLAYERS_-1)*NCLS_, logitsb, BN_, D_, NCLS_, stream, false, false);
    int tot = BN_*4 + BN_*NCLS_;
    write_out_kernel<<<(tot+255)/256,256,0,stream>>>(refd, logitsb, (float*)d_out);
}

// Round 6
// 3160.012 us; speedup vs baseline: 2.6834x; 1.3101x over previous
//
#include <hip/hip_runtime.h>
#include <hip/hip_bf16.h>

typedef __hip_bfloat16 bf16;
typedef short short8 __attribute__((ext_vector_type(8)));
typedef short short4v __attribute__((ext_vector_type(4)));
typedef float float4v __attribute__((ext_vector_type(4)));

#define D_ 256
#define NHEAD_ 8
#define DH_ 32
#define NQ_ 300
#define NLAYERS_ 6
#define DFF_ 1024
#define NCLS_ 80
#define BS_ 16
#define LM_ 8400
#define BN_ (BS_*NQ_)   // 4800

static __device__ __forceinline__ short f2bf(float x){
    union{float f; unsigned u;} v; v.f = x;
    unsigned r = v.u + 0x7FFF + ((v.u>>16)&1);
    return (short)(r>>16);
}
static __device__ __forceinline__ float bf2f(short s){
    union{unsigned u; float f;} v; v.u = ((unsigned)(unsigned short)s)<<16; return v.f;
}

// ================= MFMA bf16 GEMM =================
// A: (M,K) f32 (optional A2 add, A3 alt for n0>=nA2lim) or bf16 ; WT: (N,K) bf16
// bias 3-way split at ns1/ns2 ; C: f32 or bf16 ; blockIdx.z strides for batching.
#define LSTR 40

template<int TM, bool ABF16, bool RELU, bool OUTBF16>
__global__ __launch_bounds__(256) void mfma_gemm_kernel(
    const void* __restrict__ Av, const void* __restrict__ A2v,
    const void* __restrict__ A3v, int nA2lim,
    const short* __restrict__ WT, size_t zWT,
    const float* __restrict__ b0, const float* __restrict__ b1,
    const float* __restrict__ b2, int ns1, int ns2, size_t zB,
    void* __restrict__ Cv, size_t zC, int M, int K, int N)
{
    __shared__ short As[TM*LSTR];
    __shared__ short Bs[128*LSTR];
    int zz = blockIdx.z;
    WT += (size_t)zz*zWT; b0 += (size_t)zz*zB; b1 += (size_t)zz*zB; b2 += (size_t)zz*zB;
    int tid = threadIdx.x;
    int lane = tid&63, wave = tid>>6;
    int m0 = blockIdx.y*TM, n0 = blockIdx.x*128;
    const int MI = TM/32;
    int wm = (wave>>1)*(TM/2), wn = (wave&1)*64;
    int lr = lane&15, lq = lane>>4;
    float4v acc[MI][4];
    #pragma unroll
    for(int i=0;i<MI;i++)
        #pragma unroll
        for(int j=0;j<4;j++){ acc[i][j].x=0.f; acc[i][j].y=0.f; acc[i][j].z=0.f; acc[i][j].w=0.f; }

    const float* Af; const float* Ad; const short* Ah;
    if(ABF16){ Ah = (const short*)Av; Af=nullptr; Ad=nullptr; }
    else {
        Af = (n0 < nA2lim)? (const float*)Av : (const float*)A3v;
        Ad = (n0 < nA2lim)? (const float*)A2v : nullptr;
        Ah = nullptr;
    }

    for(int k0=0;k0<K;k0+=32){
        if(ABF16){
            #pragma unroll
            for(int it=0; it<TM/64; ++it){
                int idx = (it*256+tid)*8;
                int r = idx>>5, kk = idx&31;
                int gm = m0+r;
                short8 v = {};
                if(gm<M) v = *(const short8*)(Ah + (size_t)gm*K + (k0+kk));
                *(short8*)(&As[r*LSTR+kk]) = v;
            }
        } else {
            #pragma unroll
            for(int it=0; it<TM/32; ++it){
                int idx = (it*256+tid)*4;
                int r = idx>>5, kk = idx&31;
                int gm = m0+r;
                float4v v; v.x=0.f;v.y=0.f;v.z=0.f;v.w=0.f;
                if(gm<M){
                    v = *(const float4v*)(Af + (size_t)gm*K + (k0+kk));
                    if(Ad){
                        float4v w = *(const float4v*)(Ad + (size_t)gm*K + (k0+kk));
                        v.x+=w.x; v.y+=w.y; v.z+=w.z; v.w+=w.w;
                    }
                }
                short4v h; h.x=f2bf(v.x); h.y=f2bf(v.y); h.z=f2bf(v.z); h.w=f2bf(v.w);
                *(short4v*)(&As[r*LSTR+kk]) = h;
            }
        }
        #pragma unroll
        for(int it=0; it<2; ++it){
            int idx = (it*256+tid)*8;
            int r = idx>>5, kk = idx&31;
            int gn = n0+r;
            short8 v = {};
            if(gn<N) v = *(const short8*)(WT + (size_t)gn*K + (k0+kk));
            *(short8*)(&Bs[r*LSTR+kk]) = v;
        }
        __syncthreads();
        short8 af[MI], bfr[4];
        #pragma unroll
        for(int mi=0;mi<MI;mi++) af[mi]  = *(const short8*)(&As[(wm+mi*16+lr)*LSTR + lq*8]);
        #pragma unroll
        for(int ni=0;ni<4;ni++) bfr[ni] = *(const short8*)(&Bs[(wn+ni*16+lr)*LSTR + lq*8]);
        #pragma unroll
        for(int mi=0;mi<MI;mi++)
            #pragma unroll
            for(int ni=0;ni<4;ni++)
                acc[mi][ni] = __builtin_amdgcn_mfma_f32_16x16x32_bf16(af[mi], bfr[ni], acc[mi][ni], 0,0,0);
        __syncthreads();
    }
    float* Cf=(float*)Cv + (size_t)zz*zC; bf16* Ch=(bf16*)Cv + (size_t)zz*zC;
    #pragma unroll
    for(int mi=0;mi<MI;mi++){
        #pragma unroll
        for(int r=0;r<4;r++){
            int gm = m0+wm+mi*16+lq*4+r;
            if(gm>=M) continue;
            #pragma unroll
            for(int ni=0;ni<4;ni++){
                int gn = n0+wn+ni*16+lr;
                if(gn>=N) continue;
                float bv = (gn<ns1)? b0[gn] : ((gn<ns2)? b1[gn-ns1] : b2[gn-ns2]);
                float v = acc[mi][ni][r] + bv;
                if(RELU) v = fmaxf(v,0.f);
                if(OUTBF16) Ch[(size_t)gm*N+gn]=__float2bfloat16(v);
                else        Cf[(size_t)gm*N+gn]=v;
            }
        }
    }
}

// ================= fused MHA (union LDS, vectorized staging, bf16 out) =================
__global__ __launch_bounds__(256) void fused_mha_kernel(
    const float* __restrict__ QKV, short* __restrict__ O)
{
    const int ld = 768;
    int bh = blockIdx.y; int b = bh>>3, h = bh&7;
    int q0 = blockIdx.x*64;
    __shared__ short lds[31104];   // 62208 B
    short* Vts = lds;              // 32 x 324
    short* Qs  = lds + 10368;      // 64 x 36
    short* Ks  = lds + 12672;      // 304 x 36
    short* Ps  = lds + 10368;      // 64 x 324, overlays Qs+Ks after S-phase
    int tid = threadIdx.x;
    for(int idx=tid; idx<64*8; idx+=256){
        int r=idx>>3, c4=(idx&7)*4; int gq=q0+r;
        float4v v; v.x=0.f;v.y=0.f;v.z=0.f;v.w=0.f;
        if(gq<NQ_) v = *(const float4v*)(QKV + ((size_t)(b*NQ_+gq))*ld + h*DH_ + c4);
        short4v h4; h4.x=f2bf(v.x);h4.y=f2bf(v.y);h4.z=f2bf(v.z);h4.w=f2bf(v.w);
        *(short4v*)(Qs + r*36 + c4) = h4;
    }
    for(int idx=tid; idx<304*8; idx+=256){
        int r=idx>>3, c4=(idx&7)*4;
        float4v v; v.x=0.f;v.y=0.f;v.z=0.f;v.w=0.f;
        if(r<NQ_) v = *(const float4v*)(QKV + 256 + ((size_t)(b*NQ_+r))*ld + h*DH_ + c4);
        short4v h4; h4.x=f2bf(v.x);h4.y=f2bf(v.y);h4.z=f2bf(v.z);h4.w=f2bf(v.w);
        *(short4v*)(Ks + r*36 + c4) = h4;
    }
    for(int idx=tid; idx<320*8; idx+=256){
        int r=idx>>3, c4=(idx&7)*4;
        float4v v; v.x=0.f;v.y=0.f;v.z=0.f;v.w=0.f;
        if(r<NQ_) v = *(const float4v*)(QKV + 512 + ((size_t)(b*NQ_+r))*ld + h*DH_ + c4);
        Vts[(c4+0)*324+r]=f2bf(v.x); Vts[(c4+1)*324+r]=f2bf(v.y);
        Vts[(c4+2)*324+r]=f2bf(v.z); Vts[(c4+3)*324+r]=f2bf(v.w);
    }
    __syncthreads();

    int lane = tid&63, wave = tid>>6;
    int lr = lane&15, lq = lane>>4;
    int mrow = wave*16;
    const float scale = 0.17677669529663687f;

    float4v acc[19];
    #pragma unroll
    for(int t=0;t<19;t++){ acc[t].x=0.f; acc[t].y=0.f; acc[t].z=0.f; acc[t].w=0.f; }
    short8 afrag = *(const short8*)(&Qs[(mrow+lr)*36 + lq*8]);
    #pragma unroll
    for(int t=0;t<19;t++){
        short8 bfrag = *(const short8*)(&Ks[(t*16+lr)*36 + lq*8]);
        acc[t] = __builtin_amdgcn_mfma_f32_16x16x32_bf16(afrag, bfrag, acc[t], 0,0,0);
    }
    __syncthreads();   // Qs/Ks dead; Ps overlay becomes writable

    for(int idx=tid; idx<64*16; idx+=256){
        int r=idx>>4, c=idx&15;
        Ps[r*324 + 304 + c]=0;
    }
    #pragma unroll
    for(int t=0;t<19;t++){
        #pragma unroll
        for(int r=0;r<4;r++) acc[t][r] *= scale;
    }
    if(lr>=12){
        #pragma unroll
        for(int r=0;r<4;r++) acc[18][r] = -1e30f;
    }
    float mx[4];
    #pragma unroll
    for(int r=0;r<4;r++){
        float m = acc[0][r];
        #pragma unroll
        for(int t=1;t<19;t++) m = fmaxf(m, acc[t][r]);
        m = fmaxf(m, __shfl_xor(m,1)); m = fmaxf(m, __shfl_xor(m,2));
        m = fmaxf(m, __shfl_xor(m,4)); m = fmaxf(m, __shfl_xor(m,8));
        mx[r]=m;
    }
    float sum[4] = {0.f,0.f,0.f,0.f};
    #pragma unroll
    for(int t=0;t<19;t++){
        #pragma unroll
        for(int r=0;r<4;r++){
            float p = __expf(acc[t][r]-mx[r]);
            acc[t][r]=p; sum[r]+=p;
        }
    }
    #pragma unroll
    for(int r=0;r<4;r++){
        float s = sum[r];
        s += __shfl_xor(s,1); s += __shfl_xor(s,2);
        s += __shfl_xor(s,4); s += __shfl_xor(s,8);
        sum[r] = 1.f/s;
    }
    #pragma unroll
    for(int t=0;t<19;t++){
        #pragma unroll
        for(int r=0;r<4;r++){
            Ps[(mrow + lq*4 + r)*324 + t*16 + lr] = f2bf(acc[t][r]*sum[r]);
        }
    }
    __syncthreads();
    float4v oacc[2];
    oacc[0].x=0.f;oacc[0].y=0.f;oacc[0].z=0.f;oacc[0].w=0.f;
    oacc[1]=oacc[0];
    #pragma unroll
    for(int kc=0;kc<10;kc++){
        short8 pa = *(const short8*)(&Ps[(mrow+lr)*324 + kc*32 + lq*8]);
        #pragma unroll
        for(int n=0;n<2;n++){
            short8 vb = *(const short8*)(&Vts[(n*16+lr)*324 + kc*32 + lq*8]);
            oacc[n] = __builtin_amdgcn_mfma_f32_16x16x32_bf16(pa, vb, oacc[n], 0,0,0);
        }
    }
    #pragma unroll
    for(int n=0;n<2;n++){
        #pragma unroll
        for(int r=0;r<4;r++){
            int gq = q0 + mrow + lq*4 + r;
            if(gq<NQ_)
                O[((size_t)(b*NQ_+gq))*D_ + h*DH_ + n*16 + lr] = f2bf(oacc[n][r]);
        }
    }
}

// ============== all-weights transpose f32[K][N] -> bf16[N][K] ==============
#define NTD 74
struct TD { const float* src; unsigned dstoff; int K, N, base; };
struct TAll { TD d[NTD]; };

__global__ __launch_bounds__(256) void transpose_all_kernel(TAll p, short* __restrict__ WTb){
    int blk = blockIdx.x;
    int di = 0;
    #pragma unroll 1
    for(int i=0;i<NTD;i++){ if(blk >= p.d[i].base) di = i; }
    TD d = p.d[di];
    int rel = blk - d.base;
    int ntx = (d.N+31)/32;
    int tn = (rel % ntx)*32, tk = (rel / ntx)*32;
    __shared__ float t[32][33];
    int tx = threadIdx.x&31, ty = threadIdx.x>>5;
    for(int i=0;i<32;i+=8){
        int k = tk+ty+i, n = tn+tx;
        t[ty+i][tx] = (k<d.K && n<d.N)? d.src[(size_t)k*d.N+n] : 0.f;
    }
    __syncthreads();
    short* out = WTb + d.dstoff;
    for(int i=0;i<32;i+=8){
        int n = tn+ty+i, k = tk+tx;
        if(n<d.N && k<d.K) out[(size_t)n*d.K+k] = f2bf(t[tx][ty+i]);
    }
}

// ================= SIMT GEMM (tiny K/N) =================
template<bool RELU>
__global__ __launch_bounds__(256) void gemm_kernel(
    const float* __restrict__ A, const float* __restrict__ W,
    const float* __restrict__ bias, float* __restrict__ Cf,
    int M, int K, int N)
{
    __shared__ float As[16][68];
    __shared__ float Bs[16][68];
    int tid = threadIdx.x;
    int m0 = blockIdx.y*64, n0 = blockIdx.x*64;
    int tm = tid>>4, tn = tid&15;
    float acc[4][4] = {};
    int lam = tid>>2;
    int lak = (tid&3)*4;
    int lbk = tid>>4;
    int lbn = (tid&15)*4;
    for(int k0=0;k0<K;k0+=16){
        {
            int m = m0+lam;
            #pragma unroll
            for(int j=0;j<4;j++){
                int k = k0+lak+j;
                float v=0.f;
                if(m<M && k<K) v = A[(size_t)m*K+k];
                As[lak+j][lam]=v;
            }
        }
        {
            int k = k0+lbk;
            #pragma unroll
            for(int j=0;j<4;j++){
                int n = n0+lbn+j;
                float v=0.f;
                if(k<K && n<N) v = W[(size_t)k*N+n];
                Bs[lbk][lbn+j]=v;
            }
        }
        __syncthreads();
        #pragma unroll
        for(int kk=0;kk<16;kk++){
            float a[4], bb[4];
            #pragma unroll
            for(int i=0;i<4;i++) a[i]=As[kk][tm*4+i];
            #pragma unroll
            for(int j=0;j<4;j++) bb[j]=Bs[kk][tn*4+j];
            #pragma unroll
            for(int i=0;i<4;i++)
                #pragma unroll
                for(int j=0;j<4;j++) acc[i][j] += a[i]*bb[j];
        }
        __syncthreads();
    }
    #pragma unroll
    for(int i=0;i<4;i++){
        int m=m0+tm*4+i; if(m>=M) continue;
        #pragma unroll
        for(int j=0;j<4;j++){
            int n=n0+tn*4+j; if(n>=N) continue;
            float v = acc[i][j] + bias[n];
            if(RELU) v = fmaxf(v,0.f);
            Cf[(size_t)m*N+n]=v;
        }
    }
}

// ---------------- small elementwise kernels ----------------
__global__ void copy_kernel(const float* __restrict__ a, float* __restrict__ o, int n){
    int i = blockIdx.x*blockDim.x+threadIdx.x;
    if(i<n) o[i]=a[i];
}
__global__ void cvt_f32_bf16_kernel(const float* __restrict__ a, short* __restrict__ o, int n4){
    int i = blockIdx.x*blockDim.x+threadIdx.x;
    if(i<n4){
        float4v v = *(const float4v*)(a + (size_t)i*4);
        short4v h; h.x=f2bf(v.x); h.y=f2bf(v.y); h.z=f2bf(v.z); h.w=f2bf(v.w);
        *(short4v*)(o + (size_t)i*4) = h;
    }
}
__global__ void sigmoid_init_kernel(const float* __restrict__ a, float* __restrict__ o, int n){
    int i = blockIdx.x*blockDim.x+threadIdx.x;
    if(i<n){ float x=a[i]; o[i]=1.f/(1.f+expf(-x)); }
}
__global__ void bbox_update_kernel(float* __restrict__ refd, const float* __restrict__ delta, int n){
    int i = blockIdx.x*blockDim.x+threadIdx.x;
    if(i>=n) return;
    float x = refd[i];
    x = fminf(fmaxf(x,0.f),1.f);
    float num = fmaxf(x,1e-5f), den = fmaxf(1.f-x,1e-5f);
    float nd = delta[i] + logf(num/den);
    refd[i] = 1.f/(1.f+expf(-nd));
}
__global__ void write_out_kernel(const float* __restrict__ refd, const float* __restrict__ logits, float* __restrict__ out){
    int i = blockIdx.x*blockDim.x+threadIdx.x;
    if(i<BN_*4) out[i]=refd[i];
    else if(i<BN_*4+BN_*NCLS_) out[i]=logits[i-BN_*4];
}

// ---------------- layernorm with residual (t2 bf16) ----------------
__global__ __launch_bounds__(256) void ln_residual_kernel(
    float* __restrict__ cur, const short* __restrict__ t2b,
    const float* __restrict__ g, const float* __restrict__ b)
{
    int row = blockIdx.x; int c = threadIdx.x;
    size_t idx = (size_t)row*D_+c;
    float x = cur[idx] + bf2f(t2b[idx]);
    float v1 = x, v2 = x*x;
    #pragma unroll
    for(int o=32;o>0;o>>=1){ v1 += __shfl_down(v1,o,64); v2 += __shfl_down(v2,o,64); }
    __shared__ float s1[4], s2[4], st[2];
    int wid=c>>6, lane=c&63;
    if(lane==0){ s1[wid]=v1; s2[wid]=v2; }
    __syncthreads();
    if(c==0){
        float a=0,d=0;
        #pragma unroll
        for(int i=0;i<4;i++){a+=s1[i]; d+=s2[i];}
        st[0]=a/(float)D_; st[1]=d/(float)D_;
    }
    __syncthreads();
    float m=st[0], var=st[1]-m*m;
    float y = (x-m)*rsqrtf(var+1e-5f)*g[c] + b[c];
    cur[idx]=y;
}

// ---------------- deform attw softmax (fused off|attw buffer, stride 288) ----------------
__global__ void attw_softmax_kernel(float* __restrict__ oab){
    int t = blockIdx.x*blockDim.x+threadIdx.x;
    if(t>=BN_*NHEAD_) return;
    int row=t/NHEAD_, h=t%NHEAD_;
    float* p = oab + (size_t)row*288 + 192 + h*12;
    float m=-1e30f;
    #pragma unroll
    for(int i=0;i<12;i++) m=fmaxf(m,p[i]);
    float e[12]; float s=0.f;
    #pragma unroll
    for(int i=0;i<12;i++){ e[i]=__expf(p[i]-m); s+=e[i]; }
    float inv=1.f/s;
    #pragma unroll
    for(int i=0;i<12;i++) p[i]=e[i]*inv;
}

// ---------------- deformable sampling (bf16 out) ----------------
__global__ __launch_bounds__(256) void deform_sample_kernel(
    const float* __restrict__ refd, const float* __restrict__ oab,
    const bf16* __restrict__ value, short* __restrict__ outacc)
{
    int row = blockIdx.x; int b = row/NQ_;
    int tid = threadIdx.x; int h = tid>>5, c = tid&31;
    __shared__ float so[192], sa[96], sr[4];
    if(tid<192) so[tid]=oab[(size_t)row*288+tid];
    if(tid<96)  sa[tid]=oab[(size_t)row*288+192+tid];
    if(tid<4)   sr[tid]=refd[(size_t)row*4+tid];
    __syncthreads();
    float cx=sr[0], cy=sr[1], rw=sr[2], rh=sr[3];
    const int HS[3]={80,40,20}, WS[3]={80,40,20}, ST[3]={0,6400,8000};
    float acc=0.f;
    const bf16* vb = value + (size_t)b*LM_*D_ + h*DH_ + c;
    for(int lv=0;lv<3;lv++){
        int Hl=HS[lv], Wl=WS[lv], st=ST[lv];
        #pragma unroll
        for(int pt=0;pt<4;pt++){
            int oi = ((h*3+lv)*4+pt)*2;
            float ox=so[oi], oy=so[oi+1];
            float wa=sa[h*12+lv*4+pt];
            float lx = cx + ox*0.25f*rw*0.5f;
            float ly = cy + oy*0.25f*rh*0.5f;
            float x = lx*(float)Wl - 0.5f, y = ly*(float)Hl - 0.5f;
            float x0f=floorf(x), y0f=floorf(y);
            float wx=x-x0f, wy=y-y0f;
            int x0=(int)x0f, y0=(int)y0f;
            #pragma unroll
            for(int dy=0;dy<2;dy++){
                #pragma unroll
                for(int dx=0;dx<2;dx++){
                    int xi=x0+dx, yi=y0+dy;
                    if(xi>=0 && xi<Wl && yi>=0 && yi<Hl){
                        float w = (dx? wx : 1.f-wx)*(dy? wy : 1.f-wy);
                        int lin = yi*Wl+xi;
                        acc += __bfloat162float(vb[(size_t)(st+lin)*D_]) * (w*wa);
                    }
                }
            }
        }
    }
    outacc[(size_t)row*D_+tid]=f2bf(acc);
}

// ---------------- host helpers ----------------
static void gemm_simt(const float*A, const float*W, const float*b, float*C,
                      int M,int K,int N, hipStream_t s, bool relu){
    dim3 g((N+63)/64,(M+63)/64);
    if(relu) gemm_kernel<true><<<g,256,0,s>>>(A,W,b,C,M,K,N);
    else     gemm_kernel<false><<<g,256,0,s>>>(A,W,b,C,M,K,N);
}
// TM=64, f32 A (with optional A2 add / A3 select), 3-way bias
static void g64(const float*A, const float*A2, const float*A3, int nA2lim,
                const short*WT, const float*b0, const float*b1, const float*b2,
                int ns1, int ns2, void*C, int M,int K,int N,
                bool relu, bool outbf, hipStream_t s){
    dim3 g((N+127)/128,(M+63)/64,1);
    if(outbf)     mfma_gemm_kernel<64,false,false,true ><<<g,256,0,s>>>(A,A2,A3,nA2lim,WT,0,b0,b1,b2,ns1,ns2,0,C,0,M,K,N);
    else if(relu) mfma_gemm_kernel<64,false,true ,false><<<g,256,0,s>>>(A,A2,A3,nA2lim,WT,0,b0,b1,b2,ns1,ns2,0,C,0,M,K,N);
    else          mfma_gemm_kernel<64,false,false,false><<<g,256,0,s>>>(A,A2,A3,nA2lim,WT,0,b0,b1,b2,ns1,ns2,0,C,0,M,K,N);
}
// TM=64, bf16 A, single bias, bf16 out
static void g64b(const short*A, const short*WT, const float*b, void*C,
                 int M,int K,int N, hipStream_t s){
    dim3 g((N+127)/128,(M+63)/64,1);
    mfma_gemm_kernel<64,true,false,true><<<g,256,0,s>>>(A,nullptr,nullptr,1<<30,WT,0,b,b,b,N,N+1,0,C,0,M,K,N);
}
static int ntiles(int K,int N){ return ((N+31)/32)*((K+31)/32); }

extern "C" void kernel_launch(void* const* d_in, const int* in_sizes, int n_in,
                              void* d_out, int out_size, void* d_ws, size_t ws_size,
                              hipStream_t stream) {
    const float* tgt   = (const float*)d_in[0];
    const float* rpu   = (const float*)d_in[1];
    const float* mem   = (const float*)d_in[2];
    const float* sa_wq = (const float*)d_in[3];
    const float* sa_wk = (const float*)d_in[4];
    const float* sa_wv = (const float*)d_in[5];
    const float* sa_wo = (const float*)d_in[6];
    const float* val_w = (const float*)d_in[7];
    const float* out_w = (const float*)d_in[8];
    const float* bb_w1 = (const float*)d_in[9];
    const float* bb_w2 = (const float*)d_in[10];
    const float* sa_bq = (const float*)d_in[11];
    const float* sa_bk = (const float*)d_in[12];
    const float* sa_bv = (const float*)d_in[13];
    const float* sa_bo = (const float*)d_in[14];
    const float* ln1_b = (const float*)d_in[15];
    const float* ln2_b = (const float*)d_in[16];
    const float* ln3_b = (const float*)d_in[17];
    const float* val_b = (const float*)d_in[18];
    const float* out_b = (const float*)d_in[19];
    const float* ffn_b2= (const float*)d_in[20];
    const float* bb_b1 = (const float*)d_in[21];
    const float* bb_b2 = (const float*)d_in[22];
    const float* ln1_g = (const float*)d_in[23];
    const float* ln2_g = (const float*)d_in[24];
    const float* ln3_g = (const float*)d_in[25];
    const float* off_w = (const float*)d_in[26];
    const float* off_b = (const float*)d_in[27];
    const float* attw_w= (const float*)d_in[28];
    const float* attw_b= (const float*)d_in[29];
    const float* ffn_w1= (const float*)d_in[30];
    const float* ffn_b1= (const float*)d_in[31];
    const float* ffn_w2= (const float*)d_in[32];
    const float* bb_w3 = (const float*)d_in[33];
    const float* bb_b3 = (const float*)d_in[34];
    const float* sc_w  = (const float*)d_in[35];
    const float* sc_b  = (const float*)d_in[36];
    const float* qp_w1 = (const float*)d_in[37];
    const float* qp_b1 = (const float*)d_in[38];
    const float* qp_w2 = (const float*)d_in[39];
    const float* qp_b2 = (const float*)d_in[40];

    const size_t BND = (size_t)BN_*D_;          // 1,228,800
    const size_t USZ = (size_t)BN_*DFF_;        // 4,915,200 floats (union)
    const size_t LMD = (size_t)BS_*LM_*D_;      // 34,406,400
    const size_t LSZ = 1122304;                 // WT shorts per layer

    float* ws   = (float*)d_ws;
    float* cur  = ws;
    float* pos  = cur + BND;
    float* refd = pos + BND;
    float* U    = refd + (size_t)BN_*4;
    short* tmp16 = (short*)(U + USZ);
    short* t216  = tmp16 + BND;
    short* WT    = t216 + BND;
    short* qp2T  = WT + 6*LSZ;
    short* scT   = qp2T + 131072;
    short* X     = scT + 20480;
    // U aliases (phase-disjoint): hid512 / QKVh / offsb / ffnh / bb1,bb2,delta / logitsb
    float* hid512 = U;
    float* QKVh   = U;
    float* offsb  = U;
    float* ffnh   = U;
    float* bb1    = U;
    float* bb2    = U + BND;
    float* delta  = U + 2*BND;
    float* logitsb= U;

    size_t offX = (size_t)((char*)X - (char*)d_ws);
    int vmode;
    if(ws_size >= offX + 6*LMD*2)      vmode = 2;   // 6 value buffers, batched
    else if(ws_size >= offX + 4*LMD)   vmode = 1;   // memT + 1 value buffer
    else                               vmode = 0;   // 1 value buffer, f32 A
    short* values = X;            // vmode 2
    short* memT   = X;            // vmode 1
    short* value1 = X + LMD;      // vmode 1
    short* value0 = X;            // vmode 0

    const int nBN_D = (int)BND;
    copy_kernel<<<(nBN_D+255)/256,256,0,stream>>>(tgt, cur, nBN_D);
    sigmoid_init_kernel<<<(BN_*4+255)/256,256,0,stream>>>(rpu, refd, BN_*4);
    if(vmode==1){
        int n4 = (int)(LMD/4);
        cvt_f32_bf16_kernel<<<(n4+255)/256,256,0,stream>>>(mem, memT, n4);
    }

    // ---- transpose ALL weights upfront (one launch) ----
    {
        TAll tp; int base=0; int di=0;
        const size_t offs[12] = { 0,65536,131072,196608,262144,327680,
                                  393216,442368,466944,729088,991232,1056768 };
        const int Ks[12] = { 256,256,256,256,256,256,256,256,256,1024,256,256 };
        const int Ns[12] = { 256,256,256,256,256,256,192,96,1024,256,256,256 };
        for(int l=0;l<NLAYERS_;l++){
            const float* srcs[12] = { sa_wq+(size_t)l*D_*D_, sa_wk+(size_t)l*D_*D_, sa_wv+(size_t)l*D_*D_,
                                      sa_wo+(size_t)l*D_*D_, val_w+(size_t)l*D_*D_, out_w+(size_t)l*D_*D_,
                                      off_w+(size_t)l*D_*192, attw_w+(size_t)l*D_*96,
                                      ffn_w1+(size_t)l*D_*DFF_, ffn_w2+(size_t)l*DFF_*D_,
                                      bb_w1+(size_t)l*D_*D_, bb_w2+(size_t)l*D_*D_ };
            for(int j=0;j<12;j++){
                tp.d[di] = { srcs[j], (unsigned)(l*LSZ + offs[j]), Ks[j], Ns[j], base };
                base += ntiles(Ks[j],Ns[j]); di++;
            }
        }
        tp.d[di] = { qp_w2, (unsigned)(6*LSZ), 512, 256, base }; base += ntiles(512,256); di++;
        tp.d[di] = { sc_w + (size_t)(NLAYERS_-1)*D_*NCLS_, (unsigned)(6*LSZ+131072), 256, 80, base }; base += ntiles(256,80); di++;
        transpose_all_kernel<<<base,256,0,stream>>>(tp, WT);
    }

    // ---- value projections ----
    if(vmode==2){
        dim3 g(2,1050,6);
        mfma_gemm_kernel<128,false,false,true><<<g,256,0,stream>>>(
            mem,nullptr,mem,1<<30, WT+262144, LSZ,
            val_b,val_b,val_b, 256,257, 256, values, LMD, BS_*LM_, D_, D_);
    }

    for(int i=0;i<NLAYERS_;i++){
        const bf16* value_i;
        if(vmode==2) value_i = (const bf16*)(values + (size_t)i*LMD);
        else {
            dim3 g(2,1050,1);
            if(vmode==1){
                mfma_gemm_kernel<128,true,false,true><<<g,256,0,stream>>>(
                    memT,nullptr,nullptr,1<<30, WT+i*LSZ+262144, 0,
                    val_b+(size_t)i*D_,val_b,val_b, 256,257, 0, value1, 0, BS_*LM_, D_, D_);
                value_i = (const bf16*)value1;
            } else {
                mfma_gemm_kernel<128,false,false,true><<<g,256,0,stream>>>(
                    mem,nullptr,mem,1<<30, WT+i*LSZ+262144, 0,
                    val_b+(size_t)i*D_,val_b,val_b, 256,257, 0, value0, 0, BS_*LM_, D_, D_);
                value_i = (const bf16*)value0;
            }
        }
        // pos = MLP2(refd)
        gemm_simt(refd, qp_w1, qp_b1, hid512, BN_, 4, 512, stream, true);
        g64(hid512,nullptr,hid512,1<<30, qp2T, qp_b2,qp_b2,qp_b2, 256,257,
            pos, BN_, 512, D_, false,false, stream);
        // QKV fused: Q,K from cur+pos (n<512), V from cur
        g64(cur, pos, cur, 512, WT+i*LSZ,
            sa_bq+(size_t)i*D_, sa_bk+(size_t)i*D_, sa_bv+(size_t)i*D_, 256, 512,
            QKVh, BN_, D_, 768, false,false, stream);
        {
            dim3 g((NQ_+63)/64, BS_*NHEAD_);
            fused_mha_kernel<<<g,256,0,stream>>>(QKVh, tmp16);
        }
        g64b(tmp16, WT+i*LSZ+196608, sa_bo+(size_t)i*D_, t216, BN_, D_, D_, stream);
        ln_residual_kernel<<<BN_,256,0,stream>>>(cur, t216, ln1_g+(size_t)i*D_, ln1_b+(size_t)i*D_);
        // deformable attention: fused off|attw projection from cur+pos
        g64(cur, pos, cur, 1<<30, WT+i*LSZ+393216,
            off_b+(size_t)i*192, attw_b+(size_t)i*96, attw_b+(size_t)i*96, 192, 288,
            offsb, BN_, D_, 288, false,false, stream);
        attw_softmax_kernel<<<(BN_*NHEAD_+255)/256,256,0,stream>>>(offsb);
        deform_sample_kernel<<<BN_,256,0,stream>>>(refd, offsb, value_i, tmp16);
        g64b(tmp16, WT+i*LSZ+327680, out_b+(size_t)i*D_, t216, BN_, D_, D_, stream);
        ln_residual_kernel<<<BN_,256,0,stream>>>(cur, t216, ln2_g+(size_t)i*D_, ln2_b+(size_t)i*D_);
        // FFN
        g64(cur,nullptr,cur,1<<30, WT+i*LSZ+466944, ffn_b1+(size_t)i*DFF_,ffn_b1,ffn_b1, DFF_,DFF_+1,
            ffnh, BN_, D_, DFF_, true,false, stream);
        g64(ffnh,nullptr,ffnh,1<<30, WT+i*LSZ+729088, ffn_b2+(size_t)i*D_,ffn_b2,ffn_b2, 256,257,
            t216, BN_, DFF_, D_, false,true, stream);
        ln_residual_kernel<<<BN_,256,0,stream>>>(cur, t216, ln3_g+(size_t)i*D_, ln3_b+(size_t)i*D_);
        // bbox head
        g64(cur,nullptr,cur,1<<30, WT+i*LSZ+991232, bb_b1+(size_t)i*D_,bb_b1,bb_b1, 256,257,
            bb1, BN_, D_, D_, true,false, stream);
        g64(bb1,nullptr,bb1,1<<30, WT+i*LSZ+1056768, bb_b2+(size_t)i*D_,bb_b2,bb_b2, 256,257,
            bb2, BN_, D_, D_, true,false, stream);
        gemm_simt(bb2, bb_w3+(size_t)i*D_*4, bb_b3+(size_t)i*4, delta, BN_, D_, 4, stream, false);
        bbox_update_kernel<<<(BN_*4+255)/256,256,0,stream>>>(refd, delta, BN_*4);
    }
    g64(cur,nullptr,cur,1<<30, scT, sc_b+(size_t)(NLAYERS_-1)*NCLS_,sc_b,sc_b, NCLS_,NCLS_+1,
        logitsb, BN_, D_, NCLS_, false,false, stream);
    int tot = BN_*4 + BN_*NCLS_;
    write_out_kernel<<<(tot+255)/256,256,0,stream>>>(refd, logitsb, (float*)d_out);
}